// Round 7
// baseline (454.643 us; speedup 1.0000x reference)
//
#include <hip/hip_runtime.h>

// ---------------------------------------------------------------------------
// FlexibleGraphSAGE: 3-layer SAGEConv (mean aggregation).
//   per layer: out = mean_agg(h) @ Wl^T + bl + h @ Wr^T   (+ReLU on layers 0,1)
// R6 vs R5: FIX half-wave aggregate divergent-__shfl UB.
//   R4/R5 bug: odd-m chunks give the two wave halves different trip counts;
//   __shfl (ds_bpermute) executed with half the wave inactive reads UNDEFINED
//   data from inactive source lanes -> garbage neighbor indices (absmax 0.24).
//   Fix: uniform loop bounds for the whole wave; shfl always fully active;
//   only the load+add is guarded (j < m).
// R4: bucketed CSR build (bin by dst>>8, per-bucket LDS build).
// R3: fp16 pipeline, LDS-free MFMA 16x16x32_f16 GEMM (fp32 acc).
// ---------------------------------------------------------------------------

#define D_H 128
#define NBUCKET 196          // ceil(50000/256)
#define SUBCAP 2048          // capacity per sub-cursor (mean ~1024, +30 sigma)

typedef _Float16 half8  __attribute__((ext_vector_type(8)));
typedef _Float16 half4v __attribute__((ext_vector_type(4)));
typedef float    floatx4 __attribute__((ext_vector_type(4)));

// ---------------- CSR build (bucketed) ----------------
__global__ __launch_bounds__(256) void bin_edges_kernel(const int* __restrict__ src,
                                                        const int* __restrict__ dst,
                                                        int* __restrict__ bcnt,
                                                        unsigned int* __restrict__ bedge, int E) {
    int e = blockIdx.x * 256 + threadIdx.x;
    if (e >= E) return;
    int d = dst[e];
    int s = src[e];
    int b = d >> 8;
    int sub = threadIdx.x & 3;
    int pos = atomicAdd(&bcnt[b * 4 + sub], 1);
    bedge[(size_t)(b * 4 + sub) * SUBCAP + pos] = ((unsigned int)(d & 255) << 16) | (unsigned int)s;
}

__global__ __launch_bounds__(256) void scan_buckets_kernel(const int* __restrict__ bcnt,
                                                           int* __restrict__ boff,
                                                           int* __restrict__ row_ptr, int n) {
    __shared__ int s[256];
    int t = threadIdx.x;
    int c = 0;
    if (t < NBUCKET)
        c = bcnt[t * 4 + 0] + bcnt[t * 4 + 1] + bcnt[t * 4 + 2] + bcnt[t * 4 + 3];
    s[t] = c;
    __syncthreads();
    for (int off = 1; off < 256; off <<= 1) {
        int tmp = (t >= off) ? s[t - off] : 0;
        __syncthreads();
        s[t] += tmp;
        __syncthreads();
    }
    if (t < NBUCKET) boff[t] = s[t] - c;
    if (t == 255) row_ptr[n] = s[255];
}

__global__ __launch_bounds__(256) void bucket_build_kernel(const unsigned int* __restrict__ bedge,
                                                           const int* __restrict__ bcnt,
                                                           const int* __restrict__ boff,
                                                           int* __restrict__ row_ptr,
                                                           float* __restrict__ inv_deg,
                                                           int* __restrict__ col, int n) {
    __shared__ int sdeg[256];
    __shared__ int sscan[256];
    __shared__ int lcur[256];
    const int b = blockIdx.x;
    const int t = threadIdx.x;
    const int base = boff[b];
    sdeg[t] = 0;
    __syncthreads();
    #pragma unroll
    for (int seg = 0; seg < 4; ++seg) {
        int c = bcnt[b * 4 + seg];
        const unsigned int* p = &bedge[(size_t)(b * 4 + seg) * SUBCAP];
        for (int i = t; i < c; i += 256)
            atomicAdd(&sdeg[p[i] >> 16], 1);
    }
    __syncthreads();
    int d = sdeg[t];
    sscan[t] = d;
    __syncthreads();
    for (int off = 1; off < 256; off <<= 1) {
        int tmp = (t >= off) ? sscan[t - off] : 0;
        __syncthreads();
        sscan[t] += tmp;
        __syncthreads();
    }
    int excl = sscan[t] - d;
    int node = b * 256 + t;
    if (node < n) {
        row_ptr[node] = base + excl;
        inv_deg[node] = 1.0f / (float)max(d, 1);
    }
    lcur[t] = excl;
    __syncthreads();
    #pragma unroll
    for (int seg = 0; seg < 4; ++seg) {
        int c = bcnt[b * 4 + seg];
        const unsigned int* p = &bedge[(size_t)(b * 4 + seg) * SUBCAP];
        for (int i = t; i < c; i += 256) {
            unsigned int v = p[i];
            int pos = atomicAdd(&lcur[v >> 16], 1);
            col[base + pos] = (int)(v & 0xffffu);
        }
    }
}

// ---------------- dtype conversion ----------------
__global__ __launch_bounds__(256) void f2h4_kernel(const float* __restrict__ in,
                                                   _Float16* __restrict__ out, int n4) {
    int i = blockIdx.x * 256 + threadIdx.x;
    if (i < n4) {
        float4 v = ((const float4*)in)[i];
        half4v o = { (_Float16)v.x, (_Float16)v.y, (_Float16)v.z, (_Float16)v.w };
        ((half4v*)out)[i] = o;
    }
}

__global__ __launch_bounds__(256) void convert_weights_kernel(
        const float* __restrict__ w0, const float* __restrict__ w1,
        const float* __restrict__ w2, const float* __restrict__ w3,
        const float* __restrict__ w4, const float* __restrict__ w5,
        _Float16* __restrict__ o0, _Float16* __restrict__ o1,
        _Float16* __restrict__ o2, _Float16* __restrict__ o3,
        _Float16* __restrict__ o4, _Float16* __restrict__ o5) {
    int i = blockIdx.x * 256 + threadIdx.x;
    const float* in; _Float16* out; int base;
    if      (i <  4096) { in = w0; out = o0; base = 0; }
    else if (i <  8192) { in = w1; out = o1; base = 4096; }
    else if (i < 12288) { in = w2; out = o2; base = 8192; }
    else if (i < 16384) { in = w3; out = o3; base = 12288; }
    else if (i < 18432) { in = w4; out = o4; base = 16384; }
    else                { in = w5; out = o5; base = 18432; }
    int j = i - base;
    float4 v = ((const float4*)in)[j];
    half4v o = { (_Float16)v.x, (_Float16)v.y, (_Float16)v.z, (_Float16)v.w };
    ((half4v*)out)[j] = o;
}

// ---------------- aggregate: mean of neighbor rows ----------------
// One wave per node; 32 lanes x half4 cover a 256B row; half 0 takes even
// neighbors, half 1 odd. ALL loop bounds are uniform in m: every __shfl
// executes with the full wave active (ds_bpermute from inactive lanes is
// undefined -- the R4/R5 bug). Only the guarded load+add may diverge.
__global__ __launch_bounds__(256) void aggregate_kernel(const _Float16* __restrict__ h,
                                                        const int* __restrict__ row_ptr,
                                                        const int* __restrict__ col,
                                                        const float* __restrict__ inv_deg,
                                                        _Float16* __restrict__ agg, int n) {
    int wave = threadIdx.x >> 6;
    int lane = threadIdx.x & 63;
    int node = blockIdx.x * 4 + wave;
    if (node >= n) return;
    int beg = row_ptr[node];
    int end = row_ptr[node + 1];
    const int half = lane >> 5;
    const int off = (lane & 31) << 2;
    float ax = 0.f, ay = 0.f, az = 0.f, aw = 0.f;
    for (int base = beg; base < end; base += 64) {
        int m = end - base;
        if (m > 64) m = 64;
        int myc = (lane < m) ? col[base + lane] : 0;
        int t = 0;
        // main x4: bound m>>1 is uniform; j+6 <= m-1 for BOTH halves -> no
        // divergence, no guards.
        for (; t + 4 <= (m >> 1); t += 4) {
            int j = (t << 1) + half;
            int u0 = __shfl(myc, j + 0);
            int u1 = __shfl(myc, j + 2);
            int u2 = __shfl(myc, j + 4);
            int u3 = __shfl(myc, j + 6);
            half4v v0 = *(const half4v*)&h[(size_t)u0 * D_H + off];
            half4v v1 = *(const half4v*)&h[(size_t)u1 * D_H + off];
            half4v v2 = *(const half4v*)&h[(size_t)u2 * D_H + off];
            half4v v3 = *(const half4v*)&h[(size_t)u3 * D_H + off];
            ax += (float)v0[0] + (float)v1[0] + (float)v2[0] + (float)v3[0];
            ay += (float)v0[1] + (float)v1[1] + (float)v2[1] + (float)v3[1];
            az += (float)v0[2] + (float)v1[2] + (float)v2[2] + (float)v3[2];
            aw += (float)v0[3] + (float)v1[3] + (float)v2[3] + (float)v3[3];
        }
        // uniform tail: all 64 lanes run smax iterations; shfl pre-guard.
        int smax = (m + 1) >> 1;
        for (; t < smax; ++t) {
            int j = (t << 1) + half;          // j <= m <= 63 when guard matters
            int u = __shfl(myc, j);           // full wave active here
            if (j < m) {
                half4v v = *(const half4v*)&h[(size_t)u * D_H + off];
                ax += (float)v[0]; ay += (float)v[1];
                az += (float)v[2]; aw += (float)v[3];
            }
        }
    }
    // cross-half butterfly (uniform; lane i and i+32 hold the same slice)
    ax += __shfl(ax, lane + 32);
    ay += __shfl(ay, lane + 32);
    az += __shfl(az, lane + 32);
    aw += __shfl(aw, lane + 32);
    if (half == 0) {
        float s = inv_deg[node];
        half4v o = { (_Float16)(ax * s), (_Float16)(ay * s),
                     (_Float16)(az * s), (_Float16)(aw * s) };
        *(half4v*)&agg[(size_t)node * D_H + off] = o;
    }
}

// ---------------- MFMA GEMM (unchanged, R3-proven) ----------------
template<int NT, bool RELU_HALF_OUT>
__global__ __launch_bounds__(128) void gemm_mfma_kernel(
        const _Float16* __restrict__ Xa, const _Float16* __restrict__ Xh,
        const _Float16* __restrict__ Wa, const _Float16* __restrict__ Wh,
        const float* __restrict__ bias,
        _Float16* __restrict__ out_h, float* __restrict__ out_f, int N) {
    const int wave = threadIdx.x >> 6;
    const int lane = threadIdx.x & 63;
    const int r16 = lane & 15;
    const int quad = lane >> 4;
    const int base = blockIdx.x * 64 + wave * 32;
    const int koff = quad * 8;

    floatx4 acc[2][NT];
    #pragma unroll
    for (int s = 0; s < 2; ++s)
        #pragma unroll
        for (int j = 0; j < NT; ++j)
            acc[s][j] = (floatx4){0.f, 0.f, 0.f, 0.f};

    #pragma unroll
    for (int hsel = 0; hsel < 2; ++hsel) {
        const _Float16* __restrict__ X = hsel ? Xh : Xa;
        const _Float16* __restrict__ W = hsel ? Wh : Wa;
        #pragma unroll
        for (int k0 = 0; k0 < 128; k0 += 32) {
            half8 a0 = *(const half8*)&X[(size_t)(base + r16) * 128 + k0 + koff];
            half8 a1 = *(const half8*)&X[(size_t)(base + 16 + r16) * 128 + k0 + koff];
            #pragma unroll
            for (int j = 0; j < NT; ++j) {
                half8 b = *(const half8*)&W[(size_t)(j * 16 + r16) * 128 + k0 + koff];
                acc[0][j] = __builtin_amdgcn_mfma_f32_16x16x32_f16(a0, b, acc[0][j], 0, 0, 0);
                acc[1][j] = __builtin_amdgcn_mfma_f32_16x16x32_f16(a1, b, acc[1][j], 0, 0, 0);
            }
        }
    }

    #pragma unroll
    for (int s = 0; s < 2; ++s) {
        #pragma unroll
        for (int i = 0; i < 4; ++i) {
            int r = base + s * 16 + quad * 4 + i;
            if (r >= N) continue;
            #pragma unroll
            for (int j = 0; j < NT; ++j) {
                int c = j * 16 + r16;
                float v = acc[s][j][i] + bias[c];
                if (RELU_HALF_OUT) {
                    v = fmaxf(v, 0.f);
                    out_h[(size_t)r * (NT * 16) + c] = (_Float16)v;
                } else {
                    out_f[(size_t)r * (NT * 16) + c] = v;
                }
            }
        }
    }
}

extern "C" void kernel_launch(void* const* d_in, const int* in_sizes, int n_in,
                              void* d_out, int out_size, void* d_ws, size_t ws_size,
                              hipStream_t stream) {
    const float* x   = (const float*)d_in[0];
    const int*   edge = (const int*)d_in[1];   // int32: [2, E]
    const float* Wl0 = (const float*)d_in[2];
    const float* bl0 = (const float*)d_in[3];
    const float* Wr0 = (const float*)d_in[4];
    const float* Wl1 = (const float*)d_in[5];
    const float* bl1 = (const float*)d_in[6];
    const float* Wr1 = (const float*)d_in[7];
    const float* Wl2 = (const float*)d_in[8];
    const float* bl2 = (const float*)d_in[9];
    const float* Wr2 = (const float*)d_in[10];
    float* out = (float*)d_out;

    const int N = in_sizes[0] / D_H;   // 50000
    const int E = in_sizes[1] / 2;     // 800000
    const int* src = edge;
    const int* dst = edge + E;

    const int gx = (N + 63) / 64;
    const int Np = gx * 64;
    const size_t HBYTES = (size_t)Np * D_H * 2;   // 12.8MB per fp16 node matrix

    // ---- time-multiplexed workspace (~42MB) ----
    char* w = (char*)d_ws;
    char* P0 = w;  w += HBYTES;
    char* P1 = w;  w += HBYTES;
    char* P2 = w;  w += HBYTES;
    _Float16* Wl0h = (_Float16*)w;  w += (size_t)128 * 128 * 2;
    _Float16* Wr0h = (_Float16*)w;  w += (size_t)128 * 128 * 2;
    _Float16* Wl1h = (_Float16*)w;  w += (size_t)128 * 128 * 2;
    _Float16* Wr1h = (_Float16*)w;  w += (size_t)128 * 128 * 2;
    _Float16* Wl2h = (_Float16*)w;  w += (size_t)64 * 128 * 2;
    _Float16* Wr2h = (_Float16*)w;  w += (size_t)64 * 128 * 2;
    int* row_ptr = (int*)w;      w += (size_t)(N + 16) * 4;
    float* inv_deg = (float*)w;  w += (size_t)N * 4;
    int* col     = (int*)w;      w += (size_t)E * 4;
    int* bcnt    = (int*)w;      w += (size_t)NBUCKET * 4 * 4;
    int* boff    = (int*)w;      w += (size_t)(NBUCKET + 1) * 4;

    _Float16* xh   = (_Float16*)P0;
    _Float16* Bh   = (_Float16*)P0;          // xh dead after layer-0 GEMM
    unsigned int* bedge = (unsigned int*)P1; // 6.4MB < HBYTES
    _Float16* Ah   = (_Float16*)P1;          // bedge dead after bucket_build
    _Float16* aggh = (_Float16*)P2;

    // ---- CSR build (bucketed) ----
    hipMemsetAsync(bcnt, 0, (size_t)NBUCKET * 4 * 4, stream);
    bin_edges_kernel<<<(E + 255) / 256, 256, 0, stream>>>(src, dst, bcnt, bedge, E);
    scan_buckets_kernel<<<1, 256, 0, stream>>>(bcnt, boff, row_ptr, N);
    bucket_build_kernel<<<NBUCKET, 256, 0, stream>>>(bedge, bcnt, boff, row_ptr, inv_deg, col, N);

    // ---- fp32 -> fp16 conversions ----
    const int n4 = N * D_H / 4;
    f2h4_kernel<<<(n4 + 255) / 256, 256, 0, stream>>>(x, xh, n4);
    convert_weights_kernel<<<80, 256, 0, stream>>>(Wl0, Wr0, Wl1, Wr1, Wl2, Wr2,
                                                   Wl0h, Wr0h, Wl1h, Wr1h, Wl2h, Wr2h);

    const int agg_grid = (N + 3) / 4;

    // ---- layer 0: xh -> Ah (relu) ----
    aggregate_kernel<<<agg_grid, 256, 0, stream>>>(xh, row_ptr, col, inv_deg, aggh, N);
    gemm_mfma_kernel<8, true><<<gx, 128, 0, stream>>>(aggh, xh, Wl0h, Wr0h, bl0, Ah, nullptr, N);

    // ---- layer 1: Ah -> Bh (relu; Bh overwrites xh region) ----
    aggregate_kernel<<<agg_grid, 256, 0, stream>>>(Ah, row_ptr, col, inv_deg, aggh, N);
    gemm_mfma_kernel<8, true><<<gx, 128, 0, stream>>>(aggh, Ah, Wl1h, Wr1h, bl1, Bh, nullptr, N);

    // ---- layer 2: Bh -> out fp32 (no relu) ----
    aggregate_kernel<<<agg_grid, 256, 0, stream>>>(Bh, row_ptr, col, inv_deg, aggh, N);
    gemm_mfma_kernel<4, false><<<gx, 128, 0, stream>>>(aggh, Bh, Wl2h, Wr2h, bl2, nullptr, out, N);
}

// Round 8
// 305.291 us; speedup vs baseline: 1.4892x; 1.4892x over previous
//
#include <hip/hip_runtime.h>

// ---------------------------------------------------------------------------
// FlexibleGraphSAGE: 3-layer SAGEConv (mean aggregation).
//   per layer: out = mean_agg(h) @ Wl^T + bl + h @ Wr^T   (+ReLU on layers 0,1)
// R7 vs R6: CSR binning rewritten as deterministic counting sort.
//   R6 lesson: bin_edges' 800k global atomicAdd-with-return over 784 counters
//   = ~1020 serialized round trips per counter -> 191us, pure contention
//   (VALUBusy 0.17%, HBM 2.6%). Now: per-block LDS histogram -> exact scan ->
//   LDS-cursor scatter to precomputed offsets. ZERO global atomics anywhere.
// R6: uniform-control-flow half-wave aggregate (shfl always full-wave).
// R3: fp16 pipeline, LDS-free MFMA 16x16x32_f16 GEMM (fp32 acc).
// ---------------------------------------------------------------------------

#define D_H 128
#define NBUCKET 196          // ceil(50000/256) node buckets of 256
#define EPB 8192             // edges per histogram/scatter block
#define NBLK 98              // ceil(800000/8192)

typedef _Float16 half8  __attribute__((ext_vector_type(8)));
typedef _Float16 half4v __attribute__((ext_vector_type(4)));
typedef float    floatx4 __attribute__((ext_vector_type(4)));

// ---------------- CSR build: deterministic counting sort ----------------
// Step 1: per-block histogram of dst buckets (LDS atomics only).
__global__ __launch_bounds__(256) void hist_kernel(const int* __restrict__ dst,
                                                   int* __restrict__ histo, int E) {
    __shared__ int h[NBUCKET];
    for (int i = threadIdx.x; i < NBUCKET; i += 256) h[i] = 0;
    __syncthreads();
    int base = blockIdx.x * EPB;
    int end = min(base + EPB, E);
    for (int i = base + threadIdx.x; i < end; i += 256)
        atomicAdd(&h[dst[i] >> 8], 1);
    __syncthreads();
    for (int i = threadIdx.x; i < NBUCKET; i += 256)
        histo[blockIdx.x * NBUCKET + i] = h[i];
}

// Step 2: exact offsets. offs[b][k] = boff[k] + sum_{b'<b} histo[b'][k].
// One block; thread t owns bucket t.
__global__ __launch_bounds__(256) void scan_hist_kernel(const int* __restrict__ histo,
                                                        int* __restrict__ offs,
                                                        int* __restrict__ boff,
                                                        int* __restrict__ row_ptr, int n) {
    __shared__ int s[256];
    int t = threadIdx.x;
    int sum = 0;
    if (t < NBUCKET) {
        for (int b = 0; b < NBLK; ++b) {
            offs[b * NBUCKET + t] = sum;
            sum += histo[b * NBUCKET + t];
        }
    }
    s[t] = (t < NBUCKET) ? sum : 0;
    int tot = s[t];
    __syncthreads();
    for (int off = 1; off < 256; off <<= 1) {
        int tmp = (t >= off) ? s[t - off] : 0;
        __syncthreads();
        s[t] += tmp;
        __syncthreads();
    }
    int base = s[t] - tot;
    if (t < NBUCKET) boff[t] = base;
    if (t == 255) { boff[NBUCKET] = s[255]; row_ptr[n] = s[255]; }
    __syncthreads();
    if (t < NBUCKET)
        for (int b = 0; b < NBLK; ++b)
            offs[b * NBUCKET + t] += base;
}

// Step 3: scatter edges to their deterministic bucket segments.
// LDS cursors seeded from offs; (block,bucket) runs are contiguous -> WC ok.
__global__ __launch_bounds__(256) void scatter_kernel(const int* __restrict__ src,
                                                      const int* __restrict__ dst,
                                                      const int* __restrict__ offs,
                                                      unsigned int* __restrict__ bedge, int E) {
    __shared__ int lcur[NBUCKET];
    for (int i = threadIdx.x; i < NBUCKET; i += 256)
        lcur[i] = offs[blockIdx.x * NBUCKET + i];
    __syncthreads();
    int base = blockIdx.x * EPB;
    int end = min(base + EPB, E);
    for (int i = base + threadIdx.x; i < end; i += 256) {
        int d = dst[i];
        int pos = atomicAdd(&lcur[d >> 8], 1);
        bedge[pos] = ((unsigned int)(d & 255) << 16) | (unsigned int)src[i];
    }
}

// Step 4: per-bucket block builds deg/row_ptr/inv_deg and fills col.
__global__ __launch_bounds__(256) void bucket_build_kernel(const unsigned int* __restrict__ bedge,
                                                           const int* __restrict__ boff,
                                                           int* __restrict__ row_ptr,
                                                           float* __restrict__ inv_deg,
                                                           int* __restrict__ col, int n) {
    __shared__ int sdeg[256];
    __shared__ int sscan[256];
    __shared__ int lcur[256];
    const int b = blockIdx.x;
    const int t = threadIdx.x;
    const int base = boff[b];
    const int bend = boff[b + 1];
    sdeg[t] = 0;
    __syncthreads();
    for (int i = base + t; i < bend; i += 256)
        atomicAdd(&sdeg[bedge[i] >> 16], 1);
    __syncthreads();
    int d = sdeg[t];
    sscan[t] = d;
    __syncthreads();
    for (int off = 1; off < 256; off <<= 1) {
        int tmp = (t >= off) ? sscan[t - off] : 0;
        __syncthreads();
        sscan[t] += tmp;
        __syncthreads();
    }
    int excl = sscan[t] - d;
    int node = b * 256 + t;
    if (node < n) {
        row_ptr[node] = base + excl;
        inv_deg[node] = 1.0f / (float)max(d, 1);
    }
    lcur[t] = excl;
    __syncthreads();
    for (int i = base + t; i < bend; i += 256) {
        unsigned int v = bedge[i];
        int pos = atomicAdd(&lcur[v >> 16], 1);
        col[base + pos] = (int)(v & 0xffffu);
    }
}

// ---------------- dtype conversion ----------------
__global__ __launch_bounds__(256) void f2h4_kernel(const float* __restrict__ in,
                                                   _Float16* __restrict__ out, int n4) {
    int i = blockIdx.x * 256 + threadIdx.x;
    if (i < n4) {
        float4 v = ((const float4*)in)[i];
        half4v o = { (_Float16)v.x, (_Float16)v.y, (_Float16)v.z, (_Float16)v.w };
        ((half4v*)out)[i] = o;
    }
}

__global__ __launch_bounds__(256) void convert_weights_kernel(
        const float* __restrict__ w0, const float* __restrict__ w1,
        const float* __restrict__ w2, const float* __restrict__ w3,
        const float* __restrict__ w4, const float* __restrict__ w5,
        _Float16* __restrict__ o0, _Float16* __restrict__ o1,
        _Float16* __restrict__ o2, _Float16* __restrict__ o3,
        _Float16* __restrict__ o4, _Float16* __restrict__ o5) {
    int i = blockIdx.x * 256 + threadIdx.x;
    const float* in; _Float16* out; int base;
    if      (i <  4096) { in = w0; out = o0; base = 0; }
    else if (i <  8192) { in = w1; out = o1; base = 4096; }
    else if (i < 12288) { in = w2; out = o2; base = 8192; }
    else if (i < 16384) { in = w3; out = o3; base = 12288; }
    else if (i < 18432) { in = w4; out = o4; base = 16384; }
    else                { in = w5; out = o5; base = 18432; }
    int j = i - base;
    float4 v = ((const float4*)in)[j];
    half4v o = { (_Float16)v.x, (_Float16)v.y, (_Float16)v.z, (_Float16)v.w };
    ((half4v*)out)[j] = o;
}

// ---------------- aggregate: mean of neighbor rows (R6-proven) ----------------
__global__ __launch_bounds__(256) void aggregate_kernel(const _Float16* __restrict__ h,
                                                        const int* __restrict__ row_ptr,
                                                        const int* __restrict__ col,
                                                        const float* __restrict__ inv_deg,
                                                        _Float16* __restrict__ agg, int n) {
    int wave = threadIdx.x >> 6;
    int lane = threadIdx.x & 63;
    int node = blockIdx.x * 4 + wave;
    if (node >= n) return;
    int beg = row_ptr[node];
    int end = row_ptr[node + 1];
    const int half = lane >> 5;
    const int off = (lane & 31) << 2;
    float ax = 0.f, ay = 0.f, az = 0.f, aw = 0.f;
    for (int base = beg; base < end; base += 64) {
        int m = end - base;
        if (m > 64) m = 64;
        int myc = (lane < m) ? col[base + lane] : 0;
        int t = 0;
        for (; t + 4 <= (m >> 1); t += 4) {
            int j = (t << 1) + half;
            int u0 = __shfl(myc, j + 0);
            int u1 = __shfl(myc, j + 2);
            int u2 = __shfl(myc, j + 4);
            int u3 = __shfl(myc, j + 6);
            half4v v0 = *(const half4v*)&h[(size_t)u0 * D_H + off];
            half4v v1 = *(const half4v*)&h[(size_t)u1 * D_H + off];
            half4v v2 = *(const half4v*)&h[(size_t)u2 * D_H + off];
            half4v v3 = *(const half4v*)&h[(size_t)u3 * D_H + off];
            ax += (float)v0[0] + (float)v1[0] + (float)v2[0] + (float)v3[0];
            ay += (float)v0[1] + (float)v1[1] + (float)v2[1] + (float)v3[1];
            az += (float)v0[2] + (float)v1[2] + (float)v2[2] + (float)v3[2];
            aw += (float)v0[3] + (float)v1[3] + (float)v2[3] + (float)v3[3];
        }
        int smax = (m + 1) >> 1;
        for (; t < smax; ++t) {
            int j = (t << 1) + half;
            int u = __shfl(myc, j);           // full wave active
            if (j < m) {
                half4v v = *(const half4v*)&h[(size_t)u * D_H + off];
                ax += (float)v[0]; ay += (float)v[1];
                az += (float)v[2]; aw += (float)v[3];
            }
        }
    }
    ax += __shfl(ax, lane + 32);
    ay += __shfl(ay, lane + 32);
    az += __shfl(az, lane + 32);
    aw += __shfl(aw, lane + 32);
    if (half == 0) {
        float s = inv_deg[node];
        half4v o = { (_Float16)(ax * s), (_Float16)(ay * s),
                     (_Float16)(az * s), (_Float16)(aw * s) };
        *(half4v*)&agg[(size_t)node * D_H + off] = o;
    }
}

// ---------------- MFMA GEMM (R3-proven) ----------------
template<int NT, bool RELU_HALF_OUT>
__global__ __launch_bounds__(128) void gemm_mfma_kernel(
        const _Float16* __restrict__ Xa, const _Float16* __restrict__ Xh,
        const _Float16* __restrict__ Wa, const _Float16* __restrict__ Wh,
        const float* __restrict__ bias,
        _Float16* __restrict__ out_h, float* __restrict__ out_f, int N) {
    const int wave = threadIdx.x >> 6;
    const int lane = threadIdx.x & 63;
    const int r16 = lane & 15;
    const int quad = lane >> 4;
    const int base = blockIdx.x * 64 + wave * 32;
    const int koff = quad * 8;

    floatx4 acc[2][NT];
    #pragma unroll
    for (int s = 0; s < 2; ++s)
        #pragma unroll
        for (int j = 0; j < NT; ++j)
            acc[s][j] = (floatx4){0.f, 0.f, 0.f, 0.f};

    #pragma unroll
    for (int hsel = 0; hsel < 2; ++hsel) {
        const _Float16* __restrict__ X = hsel ? Xh : Xa;
        const _Float16* __restrict__ W = hsel ? Wh : Wa;
        #pragma unroll
        for (int k0 = 0; k0 < 128; k0 += 32) {
            half8 a0 = *(const half8*)&X[(size_t)(base + r16) * 128 + k0 + koff];
            half8 a1 = *(const half8*)&X[(size_t)(base + 16 + r16) * 128 + k0 + koff];
            #pragma unroll
            for (int j = 0; j < NT; ++j) {
                half8 b = *(const half8*)&W[(size_t)(j * 16 + r16) * 128 + k0 + koff];
                acc[0][j] = __builtin_amdgcn_mfma_f32_16x16x32_f16(a0, b, acc[0][j], 0, 0, 0);
                acc[1][j] = __builtin_amdgcn_mfma_f32_16x16x32_f16(a1, b, acc[1][j], 0, 0, 0);
            }
        }
    }

    #pragma unroll
    for (int s = 0; s < 2; ++s) {
        #pragma unroll
        for (int i = 0; i < 4; ++i) {
            int r = base + s * 16 + quad * 4 + i;
            if (r >= N) continue;
            #pragma unroll
            for (int j = 0; j < NT; ++j) {
                int c = j * 16 + r16;
                float v = acc[s][j][i] + bias[c];
                if (RELU_HALF_OUT) {
                    v = fmaxf(v, 0.f);
                    out_h[(size_t)r * (NT * 16) + c] = (_Float16)v;
                } else {
                    out_f[(size_t)r * (NT * 16) + c] = v;
                }
            }
        }
    }
}

extern "C" void kernel_launch(void* const* d_in, const int* in_sizes, int n_in,
                              void* d_out, int out_size, void* d_ws, size_t ws_size,
                              hipStream_t stream) {
    const float* x   = (const float*)d_in[0];
    const int*   edge = (const int*)d_in[1];   // int32: [2, E]
    const float* Wl0 = (const float*)d_in[2];
    const float* bl0 = (const float*)d_in[3];
    const float* Wr0 = (const float*)d_in[4];
    const float* Wl1 = (const float*)d_in[5];
    const float* bl1 = (const float*)d_in[6];
    const float* Wr1 = (const float*)d_in[7];
    const float* Wl2 = (const float*)d_in[8];
    const float* bl2 = (const float*)d_in[9];
    const float* Wr2 = (const float*)d_in[10];
    float* out = (float*)d_out;

    const int N = in_sizes[0] / D_H;   // 50000
    const int E = in_sizes[1] / 2;     // 800000
    const int* src = edge;
    const int* dst = edge + E;

    const int gx = (N + 63) / 64;
    const int Np = gx * 64;
    const size_t HBYTES = (size_t)Np * D_H * 2;   // 12.8MB per fp16 node matrix

    // ---- time-multiplexed workspace (~42MB) ----
    char* w = (char*)d_ws;
    char* P0 = w;  w += HBYTES;
    char* P1 = w;  w += HBYTES;
    char* P2 = w;  w += HBYTES;
    _Float16* Wl0h = (_Float16*)w;  w += (size_t)128 * 128 * 2;
    _Float16* Wr0h = (_Float16*)w;  w += (size_t)128 * 128 * 2;
    _Float16* Wl1h = (_Float16*)w;  w += (size_t)128 * 128 * 2;
    _Float16* Wr1h = (_Float16*)w;  w += (size_t)128 * 128 * 2;
    _Float16* Wl2h = (_Float16*)w;  w += (size_t)64 * 128 * 2;
    _Float16* Wr2h = (_Float16*)w;  w += (size_t)64 * 128 * 2;
    int* row_ptr = (int*)w;      w += (size_t)(N + 16) * 4;
    float* inv_deg = (float*)w;  w += (size_t)N * 4;
    int* col     = (int*)w;      w += (size_t)E * 4;
    int* histo   = (int*)w;      w += (size_t)NBLK * NBUCKET * 4;
    int* offs    = (int*)w;      w += (size_t)NBLK * NBUCKET * 4;
    int* boff    = (int*)w;      w += (size_t)(NBUCKET + 1) * 4;

    _Float16* xh   = (_Float16*)P0;
    _Float16* Bh   = (_Float16*)P0;          // xh dead after layer-0 GEMM
    unsigned int* bedge = (unsigned int*)P1; // 3.2MB < HBYTES, dead after bucket_build
    _Float16* Ah   = (_Float16*)P1;
    _Float16* aggh = (_Float16*)P2;

    // ---- CSR build: counting sort (no global atomics) ----
    hist_kernel<<<NBLK, 256, 0, stream>>>(dst, histo, E);
    scan_hist_kernel<<<1, 256, 0, stream>>>(histo, offs, boff, row_ptr, N);
    scatter_kernel<<<NBLK, 256, 0, stream>>>(src, dst, offs, bedge, E);
    bucket_build_kernel<<<NBUCKET, 256, 0, stream>>>(bedge, boff, row_ptr, inv_deg, col, N);

    // ---- fp32 -> fp16 conversions ----
    const int n4 = N * D_H / 4;
    f2h4_kernel<<<(n4 + 255) / 256, 256, 0, stream>>>(x, xh, n4);
    convert_weights_kernel<<<80, 256, 0, stream>>>(Wl0, Wr0, Wl1, Wr1, Wl2, Wr2,
                                                   Wl0h, Wr0h, Wl1h, Wr1h, Wl2h, Wr2h);

    const int agg_grid = (N + 3) / 4;

    // ---- layer 0: xh -> Ah (relu) ----
    aggregate_kernel<<<agg_grid, 256, 0, stream>>>(xh, row_ptr, col, inv_deg, aggh, N);
    gemm_mfma_kernel<8, true><<<gx, 128, 0, stream>>>(aggh, xh, Wl0h, Wr0h, bl0, Ah, nullptr, N);

    // ---- layer 1: Ah -> Bh (relu; Bh overwrites xh region) ----
    aggregate_kernel<<<agg_grid, 256, 0, stream>>>(Ah, row_ptr, col, inv_deg, aggh, N);
    gemm_mfma_kernel<8, true><<<gx, 128, 0, stream>>>(aggh, Ah, Wl1h, Wr1h, bl1, Bh, nullptr, N);

    // ---- layer 2: Bh -> out fp32 (no relu) ----
    aggregate_kernel<<<agg_grid, 256, 0, stream>>>(Bh, row_ptr, col, inv_deg, aggh, N);
    gemm_mfma_kernel<4, false><<<gx, 128, 0, stream>>>(aggh, Bh, Wl2h, Wr2h, bl2, nullptr, out, N);
}

// Round 9
// 297.011 us; speedup vs baseline: 1.5307x; 1.0279x over previous
//
#include <hip/hip_runtime.h>

// ---------------------------------------------------------------------------
// FlexibleGraphSAGE: 3-layer SAGEConv (mean aggregation).
//   per layer: out = mean_agg(h) @ Wl^T + bl + h @ Wr^T   (+ReLU on layers 0,1)
// R8 vs R7:
//   - layer 2 reordered (aggregation is linear): T = B@Wl2^T (N x 64, fp16),
//     R = B@Wr2^T + bias (fp32, straight to out) in ONE dual GEMM; then
//     aggregate_add gathers 64-dim T rows (128B, half the bytes) into out.
//   - aggregate: x8-unrolled main loop -> 16 gathers in flight per wave
//     (deg mean 16 becomes one fully-pipelined iteration).
// R7: deterministic counting-sort CSR (no global atomics).
// R6: uniform-control-flow half-wave aggregate (shfl always full-wave).
// R3: fp16 pipeline, LDS-free MFMA 16x16x32_f16 GEMM (fp32 acc).
// ---------------------------------------------------------------------------

#define D_H 128
#define NBUCKET 196          // ceil(50000/256) node buckets of 256
#define EPB 8192             // edges per histogram/scatter block
#define NBLK 98              // ceil(800000/8192)

typedef _Float16 half8  __attribute__((ext_vector_type(8)));
typedef _Float16 half4v __attribute__((ext_vector_type(4)));
typedef _Float16 half2v __attribute__((ext_vector_type(2)));
typedef float    floatx4 __attribute__((ext_vector_type(4)));

// ---------------- CSR build: deterministic counting sort (R7-proven) --------
__global__ __launch_bounds__(256) void hist_kernel(const int* __restrict__ dst,
                                                   int* __restrict__ histo, int E) {
    __shared__ int h[NBUCKET];
    for (int i = threadIdx.x; i < NBUCKET; i += 256) h[i] = 0;
    __syncthreads();
    int base = blockIdx.x * EPB;
    int end = min(base + EPB, E);
    for (int i = base + threadIdx.x; i < end; i += 256)
        atomicAdd(&h[dst[i] >> 8], 1);
    __syncthreads();
    for (int i = threadIdx.x; i < NBUCKET; i += 256)
        histo[blockIdx.x * NBUCKET + i] = h[i];
}

__global__ __launch_bounds__(256) void scan_hist_kernel(const int* __restrict__ histo,
                                                        int* __restrict__ offs,
                                                        int* __restrict__ boff,
                                                        int* __restrict__ row_ptr, int n) {
    __shared__ int s[256];
    int t = threadIdx.x;
    int sum = 0;
    if (t < NBUCKET) {
        for (int b = 0; b < NBLK; ++b) {
            offs[b * NBUCKET + t] = sum;
            sum += histo[b * NBUCKET + t];
        }
    }
    s[t] = (t < NBUCKET) ? sum : 0;
    int tot = s[t];
    __syncthreads();
    for (int off = 1; off < 256; off <<= 1) {
        int tmp = (t >= off) ? s[t - off] : 0;
        __syncthreads();
        s[t] += tmp;
        __syncthreads();
    }
    int base = s[t] - tot;
    if (t < NBUCKET) boff[t] = base;
    if (t == 255) { boff[NBUCKET] = s[255]; row_ptr[n] = s[255]; }
    __syncthreads();
    if (t < NBUCKET)
        for (int b = 0; b < NBLK; ++b)
            offs[b * NBUCKET + t] += base;
}

__global__ __launch_bounds__(256) void scatter_kernel(const int* __restrict__ src,
                                                      const int* __restrict__ dst,
                                                      const int* __restrict__ offs,
                                                      unsigned int* __restrict__ bedge, int E) {
    __shared__ int lcur[NBUCKET];
    for (int i = threadIdx.x; i < NBUCKET; i += 256)
        lcur[i] = offs[blockIdx.x * NBUCKET + i];
    __syncthreads();
    int base = blockIdx.x * EPB;
    int end = min(base + EPB, E);
    for (int i = base + threadIdx.x; i < end; i += 256) {
        int d = dst[i];
        int pos = atomicAdd(&lcur[d >> 8], 1);
        bedge[pos] = ((unsigned int)(d & 255) << 16) | (unsigned int)src[i];
    }
}

__global__ __launch_bounds__(256) void bucket_build_kernel(const unsigned int* __restrict__ bedge,
                                                           const int* __restrict__ boff,
                                                           int* __restrict__ row_ptr,
                                                           float* __restrict__ inv_deg,
                                                           int* __restrict__ col, int n) {
    __shared__ int sdeg[256];
    __shared__ int sscan[256];
    __shared__ int lcur[256];
    const int b = blockIdx.x;
    const int t = threadIdx.x;
    const int base = boff[b];
    const int bend = boff[b + 1];
    sdeg[t] = 0;
    __syncthreads();
    for (int i = base + t; i < bend; i += 256)
        atomicAdd(&sdeg[bedge[i] >> 16], 1);
    __syncthreads();
    int d = sdeg[t];
    sscan[t] = d;
    __syncthreads();
    for (int off = 1; off < 256; off <<= 1) {
        int tmp = (t >= off) ? sscan[t - off] : 0;
        __syncthreads();
        sscan[t] += tmp;
        __syncthreads();
    }
    int excl = sscan[t] - d;
    int node = b * 256 + t;
    if (node < n) {
        row_ptr[node] = base + excl;
        inv_deg[node] = 1.0f / (float)max(d, 1);
    }
    lcur[t] = excl;
    __syncthreads();
    for (int i = base + t; i < bend; i += 256) {
        unsigned int v = bedge[i];
        int pos = atomicAdd(&lcur[v >> 16], 1);
        col[base + pos] = (int)(v & 0xffffu);
    }
}

// ---------------- dtype conversion ----------------
__global__ __launch_bounds__(256) void f2h4_kernel(const float* __restrict__ in,
                                                   _Float16* __restrict__ out, int n4) {
    int i = blockIdx.x * 256 + threadIdx.x;
    if (i < n4) {
        float4 v = ((const float4*)in)[i];
        half4v o = { (_Float16)v.x, (_Float16)v.y, (_Float16)v.z, (_Float16)v.w };
        ((half4v*)out)[i] = o;
    }
}

__global__ __launch_bounds__(256) void convert_weights_kernel(
        const float* __restrict__ w0, const float* __restrict__ w1,
        const float* __restrict__ w2, const float* __restrict__ w3,
        const float* __restrict__ w4, const float* __restrict__ w5,
        _Float16* __restrict__ o0, _Float16* __restrict__ o1,
        _Float16* __restrict__ o2, _Float16* __restrict__ o3,
        _Float16* __restrict__ o4, _Float16* __restrict__ o5) {
    int i = blockIdx.x * 256 + threadIdx.x;
    const float* in; _Float16* out; int base;
    if      (i <  4096) { in = w0; out = o0; base = 0; }
    else if (i <  8192) { in = w1; out = o1; base = 4096; }
    else if (i < 12288) { in = w2; out = o2; base = 8192; }
    else if (i < 16384) { in = w3; out = o3; base = 12288; }
    else if (i < 18432) { in = w4; out = o4; base = 16384; }
    else                { in = w5; out = o5; base = 18432; }
    int j = i - base;
    float4 v = ((const float4*)in)[j];
    half4v o = { (_Float16)v.x, (_Float16)v.y, (_Float16)v.z, (_Float16)v.w };
    ((half4v*)out)[j] = o;
}

// ---------------- aggregate: mean of neighbor rows (128-dim) ----------------
// One wave per node; 32 lanes x half4 cover a 256B row; half 0 even neighbors,
// half 1 odd. Uniform loop bounds (R6 shfl rule). x8 main loop: 16 gathers in
// flight per wave (deg mean 16 = one iteration).
__global__ __launch_bounds__(256) void aggregate_kernel(const _Float16* __restrict__ h,
                                                        const int* __restrict__ row_ptr,
                                                        const int* __restrict__ col,
                                                        const float* __restrict__ inv_deg,
                                                        _Float16* __restrict__ agg, int n) {
    int wave = threadIdx.x >> 6;
    int lane = threadIdx.x & 63;
    int node = blockIdx.x * 4 + wave;
    if (node >= n) return;
    int beg = row_ptr[node];
    int end = row_ptr[node + 1];
    const int half = lane >> 5;
    const int off = (lane & 31) << 2;
    float ax = 0.f, ay = 0.f, az = 0.f, aw = 0.f;
    for (int base = beg; base < end; base += 64) {
        int m = end - base;
        if (m > 64) m = 64;
        int myc = (lane < m) ? col[base + lane] : 0;
        int t = 0;
        // x8 main: 8 gathers per half (16 per wave) in flight. j+14 <= m-1.
        for (; t + 8 <= (m >> 1); t += 8) {
            int j = (t << 1) + half;
            int u0 = __shfl(myc, j + 0),  u1 = __shfl(myc, j + 2);
            int u2 = __shfl(myc, j + 4),  u3 = __shfl(myc, j + 6);
            int u4 = __shfl(myc, j + 8),  u5 = __shfl(myc, j + 10);
            int u6 = __shfl(myc, j + 12), u7 = __shfl(myc, j + 14);
            half4v v0 = *(const half4v*)&h[(size_t)u0 * D_H + off];
            half4v v1 = *(const half4v*)&h[(size_t)u1 * D_H + off];
            half4v v2 = *(const half4v*)&h[(size_t)u2 * D_H + off];
            half4v v3 = *(const half4v*)&h[(size_t)u3 * D_H + off];
            half4v v4 = *(const half4v*)&h[(size_t)u4 * D_H + off];
            half4v v5 = *(const half4v*)&h[(size_t)u5 * D_H + off];
            half4v v6 = *(const half4v*)&h[(size_t)u6 * D_H + off];
            half4v v7 = *(const half4v*)&h[(size_t)u7 * D_H + off];
            ax += (float)v0[0] + (float)v1[0] + (float)v2[0] + (float)v3[0]
                + (float)v4[0] + (float)v5[0] + (float)v6[0] + (float)v7[0];
            ay += (float)v0[1] + (float)v1[1] + (float)v2[1] + (float)v3[1]
                + (float)v4[1] + (float)v5[1] + (float)v6[1] + (float)v7[1];
            az += (float)v0[2] + (float)v1[2] + (float)v2[2] + (float)v3[2]
                + (float)v4[2] + (float)v5[2] + (float)v6[2] + (float)v7[2];
            aw += (float)v0[3] + (float)v1[3] + (float)v2[3] + (float)v3[3]
                + (float)v4[3] + (float)v5[3] + (float)v6[3] + (float)v7[3];
        }
        // x4 middle
        for (; t + 4 <= (m >> 1); t += 4) {
            int j = (t << 1) + half;
            int u0 = __shfl(myc, j + 0), u1 = __shfl(myc, j + 2);
            int u2 = __shfl(myc, j + 4), u3 = __shfl(myc, j + 6);
            half4v v0 = *(const half4v*)&h[(size_t)u0 * D_H + off];
            half4v v1 = *(const half4v*)&h[(size_t)u1 * D_H + off];
            half4v v2 = *(const half4v*)&h[(size_t)u2 * D_H + off];
            half4v v3 = *(const half4v*)&h[(size_t)u3 * D_H + off];
            ax += (float)v0[0] + (float)v1[0] + (float)v2[0] + (float)v3[0];
            ay += (float)v0[1] + (float)v1[1] + (float)v2[1] + (float)v3[1];
            az += (float)v0[2] + (float)v1[2] + (float)v2[2] + (float)v3[2];
            aw += (float)v0[3] + (float)v1[3] + (float)v2[3] + (float)v3[3];
        }
        // uniform tail; shfl full-wave, load+add guarded
        int smax = (m + 1) >> 1;
        for (; t < smax; ++t) {
            int j = (t << 1) + half;
            int u = __shfl(myc, j);
            if (j < m) {
                half4v v = *(const half4v*)&h[(size_t)u * D_H + off];
                ax += (float)v[0]; ay += (float)v[1];
                az += (float)v[2]; aw += (float)v[3];
            }
        }
    }
    ax += __shfl(ax, lane + 32);
    ay += __shfl(ay, lane + 32);
    az += __shfl(az, lane + 32);
    aw += __shfl(aw, lane + 32);
    if (half == 0) {
        float s = inv_deg[node];
        half4v o = { (_Float16)(ax * s), (_Float16)(ay * s),
                     (_Float16)(az * s), (_Float16)(aw * s) };
        *(half4v*)&agg[(size_t)node * D_H + off] = o;
    }
}

// ---------------- aggregate-add: out[node] += inv_deg * sum T[neighbors] ----
// 64-dim rows (128B): 32 lanes x half2. Same uniform-shfl structure.
__global__ __launch_bounds__(256) void aggregate_add64_kernel(
        const _Float16* __restrict__ T,
        const int* __restrict__ row_ptr,
        const int* __restrict__ col,
        const float* __restrict__ inv_deg,
        float* __restrict__ out, int n) {
    int wave = threadIdx.x >> 6;
    int lane = threadIdx.x & 63;
    int node = blockIdx.x * 4 + wave;
    if (node >= n) return;
    int beg = row_ptr[node];
    int end = row_ptr[node + 1];
    const int half = lane >> 5;
    const int off = (lane & 31) << 1;     // half2 slice of 64-dim row
    float ax = 0.f, ay = 0.f;
    for (int base = beg; base < end; base += 64) {
        int m = end - base;
        if (m > 64) m = 64;
        int myc = (lane < m) ? col[base + lane] : 0;
        int t = 0;
        for (; t + 8 <= (m >> 1); t += 8) {
            int j = (t << 1) + half;
            int u0 = __shfl(myc, j + 0),  u1 = __shfl(myc, j + 2);
            int u2 = __shfl(myc, j + 4),  u3 = __shfl(myc, j + 6);
            int u4 = __shfl(myc, j + 8),  u5 = __shfl(myc, j + 10);
            int u6 = __shfl(myc, j + 12), u7 = __shfl(myc, j + 14);
            half2v v0 = *(const half2v*)&T[(size_t)u0 * 64 + off];
            half2v v1 = *(const half2v*)&T[(size_t)u1 * 64 + off];
            half2v v2 = *(const half2v*)&T[(size_t)u2 * 64 + off];
            half2v v3 = *(const half2v*)&T[(size_t)u3 * 64 + off];
            half2v v4 = *(const half2v*)&T[(size_t)u4 * 64 + off];
            half2v v5 = *(const half2v*)&T[(size_t)u5 * 64 + off];
            half2v v6 = *(const half2v*)&T[(size_t)u6 * 64 + off];
            half2v v7 = *(const half2v*)&T[(size_t)u7 * 64 + off];
            ax += (float)v0[0] + (float)v1[0] + (float)v2[0] + (float)v3[0]
                + (float)v4[0] + (float)v5[0] + (float)v6[0] + (float)v7[0];
            ay += (float)v0[1] + (float)v1[1] + (float)v2[1] + (float)v3[1]
                + (float)v4[1] + (float)v5[1] + (float)v6[1] + (float)v7[1];
        }
        for (; t + 4 <= (m >> 1); t += 4) {
            int j = (t << 1) + half;
            int u0 = __shfl(myc, j + 0), u1 = __shfl(myc, j + 2);
            int u2 = __shfl(myc, j + 4), u3 = __shfl(myc, j + 6);
            half2v v0 = *(const half2v*)&T[(size_t)u0 * 64 + off];
            half2v v1 = *(const half2v*)&T[(size_t)u1 * 64 + off];
            half2v v2 = *(const half2v*)&T[(size_t)u2 * 64 + off];
            half2v v3 = *(const half2v*)&T[(size_t)u3 * 64 + off];
            ax += (float)v0[0] + (float)v1[0] + (float)v2[0] + (float)v3[0];
            ay += (float)v0[1] + (float)v1[1] + (float)v2[1] + (float)v3[1];
        }
        int smax = (m + 1) >> 1;
        for (; t < smax; ++t) {
            int j = (t << 1) + half;
            int u = __shfl(myc, j);
            if (j < m) {
                half2v v = *(const half2v*)&T[(size_t)u * 64 + off];
                ax += (float)v[0]; ay += (float)v[1];
            }
        }
    }
    ax += __shfl(ax, lane + 32);
    ay += __shfl(ay, lane + 32);
    if (half == 0) {
        float s = inv_deg[node];
        float2* p = (float2*)&out[(size_t)node * 64 + off];
        float2 cur = *p;
        cur.x += ax * s;
        cur.y += ay * s;
        *p = cur;
    }
}

// ---------------- MFMA GEMM, layers 0/1 (R3-proven) ----------------
template<int NT, bool RELU_HALF_OUT>
__global__ __launch_bounds__(128) void gemm_mfma_kernel(
        const _Float16* __restrict__ Xa, const _Float16* __restrict__ Xh,
        const _Float16* __restrict__ Wa, const _Float16* __restrict__ Wh,
        const float* __restrict__ bias,
        _Float16* __restrict__ out_h, float* __restrict__ out_f, int N) {
    const int wave = threadIdx.x >> 6;
    const int lane = threadIdx.x & 63;
    const int r16 = lane & 15;
    const int quad = lane >> 4;
    const int base = blockIdx.x * 64 + wave * 32;
    const int koff = quad * 8;

    floatx4 acc[2][NT];
    #pragma unroll
    for (int s = 0; s < 2; ++s)
        #pragma unroll
        for (int j = 0; j < NT; ++j)
            acc[s][j] = (floatx4){0.f, 0.f, 0.f, 0.f};

    #pragma unroll
    for (int hsel = 0; hsel < 2; ++hsel) {
        const _Float16* __restrict__ X = hsel ? Xh : Xa;
        const _Float16* __restrict__ W = hsel ? Wh : Wa;
        #pragma unroll
        for (int k0 = 0; k0 < 128; k0 += 32) {
            half8 a0 = *(const half8*)&X[(size_t)(base + r16) * 128 + k0 + koff];
            half8 a1 = *(const half8*)&X[(size_t)(base + 16 + r16) * 128 + k0 + koff];
            #pragma unroll
            for (int j = 0; j < NT; ++j) {
                half8 b = *(const half8*)&W[(size_t)(j * 16 + r16) * 128 + k0 + koff];
                acc[0][j] = __builtin_amdgcn_mfma_f32_16x16x32_f16(a0, b, acc[0][j], 0, 0, 0);
                acc[1][j] = __builtin_amdgcn_mfma_f32_16x16x32_f16(a1, b, acc[1][j], 0, 0, 0);
            }
        }
    }

    #pragma unroll
    for (int s = 0; s < 2; ++s) {
        #pragma unroll
        for (int i = 0; i < 4; ++i) {
            int r = base + s * 16 + quad * 4 + i;
            if (r >= N) continue;
            #pragma unroll
            for (int j = 0; j < NT; ++j) {
                int c = j * 16 + r16;
                float v = acc[s][j][i] + bias[c];
                if (RELU_HALF_OUT) {
                    v = fmaxf(v, 0.f);
                    out_h[(size_t)r * (NT * 16) + c] = (_Float16)v;
                } else {
                    out_f[(size_t)r * (NT * 16) + c] = v;
                }
            }
        }
    }
}

// ---------------- dual GEMM, layer 2: T = B@Wl^T (fp16), R = B@Wr^T + bias ----
__global__ __launch_bounds__(128) void gemm_dual_kernel(
        const _Float16* __restrict__ B, const _Float16* __restrict__ Wl,
        const _Float16* __restrict__ Wr, const float* __restrict__ bias,
        _Float16* __restrict__ T, float* __restrict__ R, int N) {
    const int wave = threadIdx.x >> 6;
    const int lane = threadIdx.x & 63;
    const int r16 = lane & 15;
    const int quad = lane >> 4;
    const int base = blockIdx.x * 64 + wave * 32;
    const int koff = quad * 8;

    floatx4 accT[2][4], accR[2][4];
    #pragma unroll
    for (int s = 0; s < 2; ++s)
        #pragma unroll
        for (int j = 0; j < 4; ++j) {
            accT[s][j] = (floatx4){0.f, 0.f, 0.f, 0.f};
            accR[s][j] = (floatx4){0.f, 0.f, 0.f, 0.f};
        }

    #pragma unroll
    for (int k0 = 0; k0 < 128; k0 += 32) {
        half8 a0 = *(const half8*)&B[(size_t)(base + r16) * 128 + k0 + koff];
        half8 a1 = *(const half8*)&B[(size_t)(base + 16 + r16) * 128 + k0 + koff];
        #pragma unroll
        for (int j = 0; j < 4; ++j) {
            half8 bl = *(const half8*)&Wl[(size_t)(j * 16 + r16) * 128 + k0 + koff];
            half8 br = *(const half8*)&Wr[(size_t)(j * 16 + r16) * 128 + k0 + koff];
            accT[0][j] = __builtin_amdgcn_mfma_f32_16x16x32_f16(a0, bl, accT[0][j], 0, 0, 0);
            accT[1][j] = __builtin_amdgcn_mfma_f32_16x16x32_f16(a1, bl, accT[1][j], 0, 0, 0);
            accR[0][j] = __builtin_amdgcn_mfma_f32_16x16x32_f16(a0, br, accR[0][j], 0, 0, 0);
            accR[1][j] = __builtin_amdgcn_mfma_f32_16x16x32_f16(a1, br, accR[1][j], 0, 0, 0);
        }
    }

    #pragma unroll
    for (int s = 0; s < 2; ++s) {
        #pragma unroll
        for (int i = 0; i < 4; ++i) {
            int r = base + s * 16 + quad * 4 + i;
            if (r >= N) continue;
            #pragma unroll
            for (int j = 0; j < 4; ++j) {
                int c = j * 16 + r16;
                T[(size_t)r * 64 + c] = (_Float16)accT[s][j][i];
                R[(size_t)r * 64 + c] = accR[s][j][i] + bias[c];
            }
        }
    }
}

extern "C" void kernel_launch(void* const* d_in, const int* in_sizes, int n_in,
                              void* d_out, int out_size, void* d_ws, size_t ws_size,
                              hipStream_t stream) {
    const float* x   = (const float*)d_in[0];
    const int*   edge = (const int*)d_in[1];   // int32: [2, E]
    const float* Wl0 = (const float*)d_in[2];
    const float* bl0 = (const float*)d_in[3];
    const float* Wr0 = (const float*)d_in[4];
    const float* Wl1 = (const float*)d_in[5];
    const float* bl1 = (const float*)d_in[6];
    const float* Wr1 = (const float*)d_in[7];
    const float* Wl2 = (const float*)d_in[8];
    const float* bl2 = (const float*)d_in[9];
    const float* Wr2 = (const float*)d_in[10];
    float* out = (float*)d_out;

    const int N = in_sizes[0] / D_H;   // 50000
    const int E = in_sizes[1] / 2;     // 800000
    const int* src = edge;
    const int* dst = edge + E;

    const int gx = (N + 63) / 64;
    const int Np = gx * 64;
    const size_t HBYTES = (size_t)Np * D_H * 2;   // 12.8MB per fp16 node matrix

    // ---- time-multiplexed workspace (~42MB) ----
    char* w = (char*)d_ws;
    char* P0 = w;  w += HBYTES;
    char* P1 = w;  w += HBYTES;
    char* P2 = w;  w += HBYTES;
    _Float16* Wl0h = (_Float16*)w;  w += (size_t)128 * 128 * 2;
    _Float16* Wr0h = (_Float16*)w;  w += (size_t)128 * 128 * 2;
    _Float16* Wl1h = (_Float16*)w;  w += (size_t)128 * 128 * 2;
    _Float16* Wr1h = (_Float16*)w;  w += (size_t)128 * 128 * 2;
    _Float16* Wl2h = (_Float16*)w;  w += (size_t)64 * 128 * 2;
    _Float16* Wr2h = (_Float16*)w;  w += (size_t)64 * 128 * 2;
    int* row_ptr = (int*)w;      w += (size_t)(N + 16) * 4;
    float* inv_deg = (float*)w;  w += (size_t)N * 4;
    int* col     = (int*)w;      w += (size_t)E * 4;
    int* histo   = (int*)w;      w += (size_t)NBLK * NBUCKET * 4;
    int* offs    = (int*)w;      w += (size_t)NBLK * NBUCKET * 4;
    int* boff    = (int*)w;      w += (size_t)(NBUCKET + 1) * 4;

    _Float16* xh   = (_Float16*)P0;
    _Float16* Bh   = (_Float16*)P0;          // xh dead after layer-0 GEMM
    unsigned int* bedge = (unsigned int*)P1; // 3.2MB, dead after bucket_build
    _Float16* Ah   = (_Float16*)P1;
    _Float16* aggh = (_Float16*)P2;          // dead after layer-1 GEMM
    _Float16* T    = (_Float16*)P2;          // layer-2 transformed features (6.4MB)

    // ---- CSR build: counting sort (no global atomics) ----
    hist_kernel<<<NBLK, 256, 0, stream>>>(dst, histo, E);
    scan_hist_kernel<<<1, 256, 0, stream>>>(histo, offs, boff, row_ptr, N);
    scatter_kernel<<<NBLK, 256, 0, stream>>>(src, dst, offs, bedge, E);
    bucket_build_kernel<<<NBUCKET, 256, 0, stream>>>(bedge, boff, row_ptr, inv_deg, col, N);

    // ---- fp32 -> fp16 conversions ----
    const int n4 = N * D_H / 4;
    f2h4_kernel<<<(n4 + 255) / 256, 256, 0, stream>>>(x, xh, n4);
    convert_weights_kernel<<<80, 256, 0, stream>>>(Wl0, Wr0, Wl1, Wr1, Wl2, Wr2,
                                                   Wl0h, Wr0h, Wl1h, Wr1h, Wl2h, Wr2h);

    const int agg_grid = (N + 3) / 4;

    // ---- layer 0: xh -> Ah (relu) ----
    aggregate_kernel<<<agg_grid, 256, 0, stream>>>(xh, row_ptr, col, inv_deg, aggh, N);
    gemm_mfma_kernel<8, true><<<gx, 128, 0, stream>>>(aggh, xh, Wl0h, Wr0h, bl0, Ah, nullptr, N);

    // ---- layer 1: Ah -> Bh (relu; Bh overwrites xh region) ----
    aggregate_kernel<<<agg_grid, 256, 0, stream>>>(Ah, row_ptr, col, inv_deg, aggh, N);
    gemm_mfma_kernel<8, true><<<gx, 128, 0, stream>>>(aggh, Ah, Wl1h, Wr1h, bl1, Bh, nullptr, N);

    // ---- layer 2 (reordered): T = Bh@Wl2^T, out = Bh@Wr2^T + bias,
    //      then out += inv_deg * (A @ T) with 64-dim (128B) gathers ----
    gemm_dual_kernel<<<gx, 128, 0, stream>>>(Bh, Wl2h, Wr2h, bl2, T, out, N);
    aggregate_add64_kernel<<<agg_grid, 256, 0, stream>>>(T, row_ptr, col, inv_deg, out, N);
}

// Round 10
// 296.778 us; speedup vs baseline: 1.5319x; 1.0008x over previous
//
#include <hip/hip_runtime.h>

// ---------------------------------------------------------------------------
// FlexibleGraphSAGE: 3-layer SAGEConv (mean aggregation).
//   per layer: out = mean_agg(h) @ Wl^T + bl + h @ Wr^T   (+ReLU on layers 0,1)
// R9 vs R8:
//   - aggregates: __launch_bounds__(256,8) (force <=64 VGPR, 32 waves/CU) --
//     probe of occupancy-vs-fabric ceiling theory.
//   - layer 2: dual GEMM writes Rh fp16; aggregate_add64 writes out once
//     (no fp32 RMW). -38MB traffic.
//   - f2h + weight conversion merged into one dispatch.
// R8: layer-2 linearity reorder (gather 64-dim T), x8-unrolled gathers.
// R7: deterministic counting-sort CSR (no global atomics).
// R6: uniform-control-flow half-wave aggregate (shfl always full-wave).
// R3: fp16 pipeline, LDS-free MFMA 16x16x32_f16 GEMM (fp32 acc).
// ---------------------------------------------------------------------------

#define D_H 128
#define NBUCKET 196          // ceil(50000/256) node buckets of 256
#define EPB 8192             // edges per histogram/scatter block
#define NBLK 98              // ceil(800000/8192)

typedef _Float16 half8  __attribute__((ext_vector_type(8)));
typedef _Float16 half4v __attribute__((ext_vector_type(4)));
typedef _Float16 half2v __attribute__((ext_vector_type(2)));
typedef float    floatx4 __attribute__((ext_vector_type(4)));

// ---------------- CSR build: deterministic counting sort (R7-proven) --------
__global__ __launch_bounds__(256) void hist_kernel(const int* __restrict__ dst,
                                                   int* __restrict__ histo, int E) {
    __shared__ int h[NBUCKET];
    for (int i = threadIdx.x; i < NBUCKET; i += 256) h[i] = 0;
    __syncthreads();
    int base = blockIdx.x * EPB;
    int end = min(base + EPB, E);
    for (int i = base + threadIdx.x; i < end; i += 256)
        atomicAdd(&h[dst[i] >> 8], 1);
    __syncthreads();
    for (int i = threadIdx.x; i < NBUCKET; i += 256)
        histo[blockIdx.x * NBUCKET + i] = h[i];
}

__global__ __launch_bounds__(256) void scan_hist_kernel(const int* __restrict__ histo,
                                                        int* __restrict__ offs,
                                                        int* __restrict__ boff,
                                                        int* __restrict__ row_ptr, int n) {
    __shared__ int s[256];
    int t = threadIdx.x;
    int sum = 0;
    if (t < NBUCKET) {
        for (int b = 0; b < NBLK; ++b) {
            offs[b * NBUCKET + t] = sum;
            sum += histo[b * NBUCKET + t];
        }
    }
    s[t] = (t < NBUCKET) ? sum : 0;
    int tot = s[t];
    __syncthreads();
    for (int off = 1; off < 256; off <<= 1) {
        int tmp = (t >= off) ? s[t - off] : 0;
        __syncthreads();
        s[t] += tmp;
        __syncthreads();
    }
    int base = s[t] - tot;
    if (t < NBUCKET) boff[t] = base;
    if (t == 255) { boff[NBUCKET] = s[255]; row_ptr[n] = s[255]; }
    __syncthreads();
    if (t < NBUCKET)
        for (int b = 0; b < NBLK; ++b)
            offs[b * NBUCKET + t] += base;
}

__global__ __launch_bounds__(256) void scatter_kernel(const int* __restrict__ src,
                                                      const int* __restrict__ dst,
                                                      const int* __restrict__ offs,
                                                      unsigned int* __restrict__ bedge, int E) {
    __shared__ int lcur[NBUCKET];
    for (int i = threadIdx.x; i < NBUCKET; i += 256)
        lcur[i] = offs[blockIdx.x * NBUCKET + i];
    __syncthreads();
    int base = blockIdx.x * EPB;
    int end = min(base + EPB, E);
    for (int i = base + threadIdx.x; i < end; i += 256) {
        int d = dst[i];
        int pos = atomicAdd(&lcur[d >> 8], 1);
        bedge[pos] = ((unsigned int)(d & 255) << 16) | (unsigned int)src[i];
    }
}

__global__ __launch_bounds__(256) void bucket_build_kernel(const unsigned int* __restrict__ bedge,
                                                           const int* __restrict__ boff,
                                                           int* __restrict__ row_ptr,
                                                           float* __restrict__ inv_deg,
                                                           int* __restrict__ col, int n) {
    __shared__ int sdeg[256];
    __shared__ int sscan[256];
    __shared__ int lcur[256];
    const int b = blockIdx.x;
    const int t = threadIdx.x;
    const int base = boff[b];
    const int bend = boff[b + 1];
    sdeg[t] = 0;
    __syncthreads();
    for (int i = base + t; i < bend; i += 256)
        atomicAdd(&sdeg[bedge[i] >> 16], 1);
    __syncthreads();
    int d = sdeg[t];
    sscan[t] = d;
    __syncthreads();
    for (int off = 1; off < 256; off <<= 1) {
        int tmp = (t >= off) ? sscan[t - off] : 0;
        __syncthreads();
        sscan[t] += tmp;
        __syncthreads();
    }
    int excl = sscan[t] - d;
    int node = b * 256 + t;
    if (node < n) {
        row_ptr[node] = base + excl;
        inv_deg[node] = 1.0f / (float)max(d, 1);
    }
    lcur[t] = excl;
    __syncthreads();
    for (int i = base + t; i < bend; i += 256) {
        unsigned int v = bedge[i];
        int pos = atomicAdd(&lcur[v >> 16], 1);
        col[base + pos] = (int)(v & 0xffffu);
    }
}

// ---------------- conversion: x (n4 float4s) + all 6 weight matrices --------
__global__ __launch_bounds__(256) void convert_all_kernel(
        const float* __restrict__ x, _Float16* __restrict__ xh, int n4,
        const float* __restrict__ w0, const float* __restrict__ w1,
        const float* __restrict__ w2, const float* __restrict__ w3,
        const float* __restrict__ w4, const float* __restrict__ w5,
        _Float16* __restrict__ o0, _Float16* __restrict__ o1,
        _Float16* __restrict__ o2, _Float16* __restrict__ o3,
        _Float16* __restrict__ o4, _Float16* __restrict__ o5) {
    int i = blockIdx.x * 256 + threadIdx.x;
    const float* in; _Float16* out; int j;
    if (i < n4) { in = x; out = xh; j = i; }
    else {
        int k = i - n4;
        if      (k <  4096) { in = w0; out = o0; j = k; }
        else if (k <  8192) { in = w1; out = o1; j = k - 4096; }
        else if (k < 12288) { in = w2; out = o2; j = k - 8192; }
        else if (k < 16384) { in = w3; out = o3; j = k - 12288; }
        else if (k < 18432) { in = w4; out = o4; j = k - 16384; }
        else if (k < 20480) { in = w5; out = o5; j = k - 18432; }
        else return;
    }
    float4 v = ((const float4*)in)[j];
    half4v o = { (_Float16)v.x, (_Float16)v.y, (_Float16)v.z, (_Float16)v.w };
    ((half4v*)out)[j] = o;
}

// ---------------- aggregate: mean of neighbor rows (128-dim) ----------------
// One wave per node; 32 lanes x half4 cover a 256B row; half 0 even neighbors,
// half 1 odd. Uniform loop bounds (R6 shfl rule). launch_bounds(256,8):
// force <=64 VGPR -> 32 waves/CU for max gather MLP (occupancy probe).
__global__ __launch_bounds__(256, 8) void aggregate_kernel(const _Float16* __restrict__ h,
                                                           const int* __restrict__ row_ptr,
                                                           const int* __restrict__ col,
                                                           const float* __restrict__ inv_deg,
                                                           _Float16* __restrict__ agg, int n) {
    int wave = threadIdx.x >> 6;
    int lane = threadIdx.x & 63;
    int node = blockIdx.x * 4 + wave;
    if (node >= n) return;
    int beg = row_ptr[node];
    int end = row_ptr[node + 1];
    const int half = lane >> 5;
    const int off = (lane & 31) << 2;
    float ax = 0.f, ay = 0.f, az = 0.f, aw = 0.f;
    for (int base = beg; base < end; base += 64) {
        int m = end - base;
        if (m > 64) m = 64;
        int myc = (lane < m) ? col[base + lane] : 0;
        int t = 0;
        for (; t + 8 <= (m >> 1); t += 8) {
            int j = (t << 1) + half;
            int u0 = __shfl(myc, j + 0),  u1 = __shfl(myc, j + 2);
            int u2 = __shfl(myc, j + 4),  u3 = __shfl(myc, j + 6);
            int u4 = __shfl(myc, j + 8),  u5 = __shfl(myc, j + 10);
            int u6 = __shfl(myc, j + 12), u7 = __shfl(myc, j + 14);
            half4v v0 = *(const half4v*)&h[(size_t)u0 * D_H + off];
            half4v v1 = *(const half4v*)&h[(size_t)u1 * D_H + off];
            half4v v2 = *(const half4v*)&h[(size_t)u2 * D_H + off];
            half4v v3 = *(const half4v*)&h[(size_t)u3 * D_H + off];
            half4v v4 = *(const half4v*)&h[(size_t)u4 * D_H + off];
            half4v v5 = *(const half4v*)&h[(size_t)u5 * D_H + off];
            half4v v6 = *(const half4v*)&h[(size_t)u6 * D_H + off];
            half4v v7 = *(const half4v*)&h[(size_t)u7 * D_H + off];
            ax += (float)v0[0] + (float)v1[0] + (float)v2[0] + (float)v3[0]
                + (float)v4[0] + (float)v5[0] + (float)v6[0] + (float)v7[0];
            ay += (float)v0[1] + (float)v1[1] + (float)v2[1] + (float)v3[1]
                + (float)v4[1] + (float)v5[1] + (float)v6[1] + (float)v7[1];
            az += (float)v0[2] + (float)v1[2] + (float)v2[2] + (float)v3[2]
                + (float)v4[2] + (float)v5[2] + (float)v6[2] + (float)v7[2];
            aw += (float)v0[3] + (float)v1[3] + (float)v2[3] + (float)v3[3]
                + (float)v4[3] + (float)v5[3] + (float)v6[3] + (float)v7[3];
        }
        for (; t + 4 <= (m >> 1); t += 4) {
            int j = (t << 1) + half;
            int u0 = __shfl(myc, j + 0), u1 = __shfl(myc, j + 2);
            int u2 = __shfl(myc, j + 4), u3 = __shfl(myc, j + 6);
            half4v v0 = *(const half4v*)&h[(size_t)u0 * D_H + off];
            half4v v1 = *(const half4v*)&h[(size_t)u1 * D_H + off];
            half4v v2 = *(const half4v*)&h[(size_t)u2 * D_H + off];
            half4v v3 = *(const half4v*)&h[(size_t)u3 * D_H + off];
            ax += (float)v0[0] + (float)v1[0] + (float)v2[0] + (float)v3[0];
            ay += (float)v0[1] + (float)v1[1] + (float)v2[1] + (float)v3[1];
            az += (float)v0[2] + (float)v1[2] + (float)v2[2] + (float)v3[2];
            aw += (float)v0[3] + (float)v1[3] + (float)v2[3] + (float)v3[3];
        }
        int smax = (m + 1) >> 1;
        for (; t < smax; ++t) {
            int j = (t << 1) + half;
            int u = __shfl(myc, j);           // full wave active
            if (j < m) {
                half4v v = *(const half4v*)&h[(size_t)u * D_H + off];
                ax += (float)v[0]; ay += (float)v[1];
                az += (float)v[2]; aw += (float)v[3];
            }
        }
    }
    ax += __shfl(ax, lane + 32);
    ay += __shfl(ay, lane + 32);
    az += __shfl(az, lane + 32);
    aw += __shfl(aw, lane + 32);
    if (half == 0) {
        float s = inv_deg[node];
        half4v o = { (_Float16)(ax * s), (_Float16)(ay * s),
                     (_Float16)(az * s), (_Float16)(aw * s) };
        *(half4v*)&agg[(size_t)node * D_H + off] = o;
    }
}

// ---------------- layer-2 finish: out = Rh + inv_deg * sum T[neighbors] -----
// 64-dim rows (128B): 32 lanes x half2. Single write of out (no RMW).
__global__ __launch_bounds__(256, 8) void aggregate_add64_kernel(
        const _Float16* __restrict__ T,
        const _Float16* __restrict__ Rh,
        const int* __restrict__ row_ptr,
        const int* __restrict__ col,
        const float* __restrict__ inv_deg,
        float* __restrict__ out, int n) {
    int wave = threadIdx.x >> 6;
    int lane = threadIdx.x & 63;
    int node = blockIdx.x * 4 + wave;
    if (node >= n) return;
    int beg = row_ptr[node];
    int end = row_ptr[node + 1];
    const int half = lane >> 5;
    const int off = (lane & 31) << 1;     // half2 slice of 64-dim row
    float ax = 0.f, ay = 0.f;
    for (int base = beg; base < end; base += 64) {
        int m = end - base;
        if (m > 64) m = 64;
        int myc = (lane < m) ? col[base + lane] : 0;
        int t = 0;
        for (; t + 8 <= (m >> 1); t += 8) {
            int j = (t << 1) + half;
            int u0 = __shfl(myc, j + 0),  u1 = __shfl(myc, j + 2);
            int u2 = __shfl(myc, j + 4),  u3 = __shfl(myc, j + 6);
            int u4 = __shfl(myc, j + 8),  u5 = __shfl(myc, j + 10);
            int u6 = __shfl(myc, j + 12), u7 = __shfl(myc, j + 14);
            half2v v0 = *(const half2v*)&T[(size_t)u0 * 64 + off];
            half2v v1 = *(const half2v*)&T[(size_t)u1 * 64 + off];
            half2v v2 = *(const half2v*)&T[(size_t)u2 * 64 + off];
            half2v v3 = *(const half2v*)&T[(size_t)u3 * 64 + off];
            half2v v4 = *(const half2v*)&T[(size_t)u4 * 64 + off];
            half2v v5 = *(const half2v*)&T[(size_t)u5 * 64 + off];
            half2v v6 = *(const half2v*)&T[(size_t)u6 * 64 + off];
            half2v v7 = *(const half2v*)&T[(size_t)u7 * 64 + off];
            ax += (float)v0[0] + (float)v1[0] + (float)v2[0] + (float)v3[0]
                + (float)v4[0] + (float)v5[0] + (float)v6[0] + (float)v7[0];
            ay += (float)v0[1] + (float)v1[1] + (float)v2[1] + (float)v3[1]
                + (float)v4[1] + (float)v5[1] + (float)v6[1] + (float)v7[1];
        }
        for (; t + 4 <= (m >> 1); t += 4) {
            int j = (t << 1) + half;
            int u0 = __shfl(myc, j + 0), u1 = __shfl(myc, j + 2);
            int u2 = __shfl(myc, j + 4), u3 = __shfl(myc, j + 6);
            half2v v0 = *(const half2v*)&T[(size_t)u0 * 64 + off];
            half2v v1 = *(const half2v*)&T[(size_t)u1 * 64 + off];
            half2v v2 = *(const half2v*)&T[(size_t)u2 * 64 + off];
            half2v v3 = *(const half2v*)&T[(size_t)u3 * 64 + off];
            ax += (float)v0[0] + (float)v1[0] + (float)v2[0] + (float)v3[0];
            ay += (float)v0[1] + (float)v1[1] + (float)v2[1] + (float)v3[1];
        }
        int smax = (m + 1) >> 1;
        for (; t < smax; ++t) {
            int j = (t << 1) + half;
            int u = __shfl(myc, j);
            if (j < m) {
                half2v v = *(const half2v*)&T[(size_t)u * 64 + off];
                ax += (float)v[0]; ay += (float)v[1];
            }
        }
    }
    ax += __shfl(ax, lane + 32);
    ay += __shfl(ay, lane + 32);
    if (half == 0) {
        float s = inv_deg[node];
        half2v r = *(const half2v*)&Rh[(size_t)node * 64 + off];
        float2 o;
        o.x = (float)r[0] + ax * s;
        o.y = (float)r[1] + ay * s;
        *(float2*)&out[(size_t)node * 64 + off] = o;
    }
}

// ---------------- MFMA GEMM, layers 0/1 (R3-proven) ----------------
template<int NT, bool RELU_HALF_OUT>
__global__ __launch_bounds__(128) void gemm_mfma_kernel(
        const _Float16* __restrict__ Xa, const _Float16* __restrict__ Xh,
        const _Float16* __restrict__ Wa, const _Float16* __restrict__ Wh,
        const float* __restrict__ bias,
        _Float16* __restrict__ out_h, float* __restrict__ out_f, int N) {
    const int wave = threadIdx.x >> 6;
    const int lane = threadIdx.x & 63;
    const int r16 = lane & 15;
    const int quad = lane >> 4;
    const int base = blockIdx.x * 64 + wave * 32;
    const int koff = quad * 8;

    floatx4 acc[2][NT];
    #pragma unroll
    for (int s = 0; s < 2; ++s)
        #pragma unroll
        for (int j = 0; j < NT; ++j)
            acc[s][j] = (floatx4){0.f, 0.f, 0.f, 0.f};

    #pragma unroll
    for (int hsel = 0; hsel < 2; ++hsel) {
        const _Float16* __restrict__ X = hsel ? Xh : Xa;
        const _Float16* __restrict__ W = hsel ? Wh : Wa;
        #pragma unroll
        for (int k0 = 0; k0 < 128; k0 += 32) {
            half8 a0 = *(const half8*)&X[(size_t)(base + r16) * 128 + k0 + koff];
            half8 a1 = *(const half8*)&X[(size_t)(base + 16 + r16) * 128 + k0 + koff];
            #pragma unroll
            for (int j = 0; j < NT; ++j) {
                half8 b = *(const half8*)&W[(size_t)(j * 16 + r16) * 128 + k0 + koff];
                acc[0][j] = __builtin_amdgcn_mfma_f32_16x16x32_f16(a0, b, acc[0][j], 0, 0, 0);
                acc[1][j] = __builtin_amdgcn_mfma_f32_16x16x32_f16(a1, b, acc[1][j], 0, 0, 0);
            }
        }
    }

    #pragma unroll
    for (int s = 0; s < 2; ++s) {
        #pragma unroll
        for (int i = 0; i < 4; ++i) {
            int r = base + s * 16 + quad * 4 + i;
            if (r >= N) continue;
            #pragma unroll
            for (int j = 0; j < NT; ++j) {
                int c = j * 16 + r16;
                float v = acc[s][j][i] + bias[c];
                if (RELU_HALF_OUT) {
                    v = fmaxf(v, 0.f);
                    out_h[(size_t)r * (NT * 16) + c] = (_Float16)v;
                } else {
                    out_f[(size_t)r * (NT * 16) + c] = v;
                }
            }
        }
    }
}

// ---- dual GEMM, layer 2: T = B@Wl^T (fp16), Rh = B@Wr^T + bias (fp16) ----
__global__ __launch_bounds__(128) void gemm_dual_kernel(
        const _Float16* __restrict__ B, const _Float16* __restrict__ Wl,
        const _Float16* __restrict__ Wr, const float* __restrict__ bias,
        _Float16* __restrict__ T, _Float16* __restrict__ Rh, int N) {
    const int wave = threadIdx.x >> 6;
    const int lane = threadIdx.x & 63;
    const int r16 = lane & 15;
    const int quad = lane >> 4;
    const int base = blockIdx.x * 64 + wave * 32;
    const int koff = quad * 8;

    floatx4 accT[2][4], accR[2][4];
    #pragma unroll
    for (int s = 0; s < 2; ++s)
        #pragma unroll
        for (int j = 0; j < 4; ++j) {
            accT[s][j] = (floatx4){0.f, 0.f, 0.f, 0.f};
            accR[s][j] = (floatx4){0.f, 0.f, 0.f, 0.f};
        }

    #pragma unroll
    for (int k0 = 0; k0 < 128; k0 += 32) {
        half8 a0 = *(const half8*)&B[(size_t)(base + r16) * 128 + k0 + koff];
        half8 a1 = *(const half8*)&B[(size_t)(base + 16 + r16) * 128 + k0 + koff];
        #pragma unroll
        for (int j = 0; j < 4; ++j) {
            half8 bl = *(const half8*)&Wl[(size_t)(j * 16 + r16) * 128 + k0 + koff];
            half8 br = *(const half8*)&Wr[(size_t)(j * 16 + r16) * 128 + k0 + koff];
            accT[0][j] = __builtin_amdgcn_mfma_f32_16x16x32_f16(a0, bl, accT[0][j], 0, 0, 0);
            accT[1][j] = __builtin_amdgcn_mfma_f32_16x16x32_f16(a1, bl, accT[1][j], 0, 0, 0);
            accR[0][j] = __builtin_amdgcn_mfma_f32_16x16x32_f16(a0, br, accR[0][j], 0, 0, 0);
            accR[1][j] = __builtin_amdgcn_mfma_f32_16x16x32_f16(a1, br, accR[1][j], 0, 0, 0);
        }
    }

    #pragma unroll
    for (int s = 0; s < 2; ++s) {
        #pragma unroll
        for (int i = 0; i < 4; ++i) {
            int r = base + s * 16 + quad * 4 + i;
            if (r >= N) continue;
            #pragma unroll
            for (int j = 0; j < 4; ++j) {
                int c = j * 16 + r16;
                T[(size_t)r * 64 + c]  = (_Float16)accT[s][j][i];
                Rh[(size_t)r * 64 + c] = (_Float16)(accR[s][j][i] + bias[c]);
            }
        }
    }
}

extern "C" void kernel_launch(void* const* d_in, const int* in_sizes, int n_in,
                              void* d_out, int out_size, void* d_ws, size_t ws_size,
                              hipStream_t stream) {
    const float* x   = (const float*)d_in[0];
    const int*   edge = (const int*)d_in[1];   // int32: [2, E]
    const float* Wl0 = (const float*)d_in[2];
    const float* bl0 = (const float*)d_in[3];
    const float* Wr0 = (const float*)d_in[4];
    const float* Wl1 = (const float*)d_in[5];
    const float* bl1 = (const float*)d_in[6];
    const float* Wr1 = (const float*)d_in[7];
    const float* Wl2 = (const float*)d_in[8];
    const float* bl2 = (const float*)d_in[9];
    const float* Wr2 = (const float*)d_in[10];
    float* out = (float*)d_out;

    const int N = in_sizes[0] / D_H;   // 50000
    const int E = in_sizes[1] / 2;     // 800000
    const int* src = edge;
    const int* dst = edge + E;

    const int gx = (N + 63) / 64;
    const int Np = gx * 64;
    const size_t HBYTES = (size_t)Np * D_H * 2;   // 12.8MB per fp16 node matrix

    // ---- time-multiplexed workspace (~42MB) ----
    char* w = (char*)d_ws;
    char* P0 = w;  w += HBYTES;
    char* P1 = w;  w += HBYTES;
    char* P2 = w;  w += HBYTES;
    _Float16* Wl0h = (_Float16*)w;  w += (size_t)128 * 128 * 2;
    _Float16* Wr0h = (_Float16*)w;  w += (size_t)128 * 128 * 2;
    _Float16* Wl1h = (_Float16*)w;  w += (size_t)128 * 128 * 2;
    _Float16* Wr1h = (_Float16*)w;  w += (size_t)128 * 128 * 2;
    _Float16* Wl2h = (_Float16*)w;  w += (size_t)64 * 128 * 2;
    _Float16* Wr2h = (_Float16*)w;  w += (size_t)64 * 128 * 2;
    int* row_ptr = (int*)w;      w += (size_t)(N + 16) * 4;
    float* inv_deg = (float*)w;  w += (size_t)N * 4;
    int* col     = (int*)w;      w += (size_t)E * 4;
    int* histo   = (int*)w;      w += (size_t)NBLK * NBUCKET * 4;
    int* offs    = (int*)w;      w += (size_t)NBLK * NBUCKET * 4;
    int* boff    = (int*)w;      w += (size_t)(NBUCKET + 1) * 4;

    _Float16* xh   = (_Float16*)P0;
    _Float16* Bh   = (_Float16*)P0;          // xh dead after layer-0 GEMM
    unsigned int* bedge = (unsigned int*)P1; // 3.2MB, dead after bucket_build
    _Float16* Ah   = (_Float16*)P1;
    _Float16* aggh = (_Float16*)P2;          // dead after layer-1 GEMM
    _Float16* T    = (_Float16*)P2;                       // layer-2 T (6.4MB)
    _Float16* Rh   = (_Float16*)(P2 + HBYTES / 2);        // layer-2 Rh (6.4MB)

    // ---- CSR build: counting sort (no global atomics) ----
    hist_kernel<<<NBLK, 256, 0, stream>>>(dst, histo, E);
    scan_hist_kernel<<<1, 256, 0, stream>>>(histo, offs, boff, row_ptr, N);
    scatter_kernel<<<NBLK, 256, 0, stream>>>(src, dst, offs, bedge, E);
    bucket_build_kernel<<<NBUCKET, 256, 0, stream>>>(bedge, boff, row_ptr, inv_deg, col, N);

    // ---- fp32 -> fp16 conversions (x + all weights, one dispatch) ----
    const int n4 = N * D_H / 4;
    const int ctotal = n4 + 20480;
    convert_all_kernel<<<(ctotal + 255) / 256, 256, 0, stream>>>(
        x, xh, n4, Wl0, Wr0, Wl1, Wr1, Wl2, Wr2,
        Wl0h, Wr0h, Wl1h, Wr1h, Wl2h, Wr2h);

    const int agg_grid = (N + 3) / 4;

    // ---- layer 0: xh -> Ah (relu) ----
    aggregate_kernel<<<agg_grid, 256, 0, stream>>>(xh, row_ptr, col, inv_deg, aggh, N);
    gemm_mfma_kernel<8, true><<<gx, 128, 0, stream>>>(aggh, xh, Wl0h, Wr0h, bl0, Ah, nullptr, N);

    // ---- layer 1: Ah -> Bh (relu; Bh overwrites xh region) ----
    aggregate_kernel<<<agg_grid, 256, 0, stream>>>(Ah, row_ptr, col, inv_deg, aggh, N);
    gemm_mfma_kernel<8, true><<<gx, 128, 0, stream>>>(aggh, Ah, Wl1h, Wr1h, bl1, Bh, nullptr, N);

    // ---- layer 2 (reordered): T = Bh@Wl2^T, Rh = Bh@Wr2^T + bias (both fp16),
    //      then out = Rh + inv_deg * (A @ T) with 64-dim (128B) gathers ----
    gemm_dual_kernel<<<gx, 128, 0, stream>>>(Bh, Wl2h, Wr2h, bl2, T, Rh, N);
    aggregate_add64_kernel<<<agg_grid, 256, 0, stream>>>(T, Rh, row_ptr, col, inv_deg, out, N);
}

// Round 11
// 295.565 us; speedup vs baseline: 1.5382x; 1.0041x over previous
//
#include <hip/hip_runtime.h>

// ---------------------------------------------------------------------------
// FlexibleGraphSAGE: 3-layer SAGEConv (mean aggregation).
//   per layer: out = mean_agg(h) @ Wl^T + bl + h @ Wr^T   (+ReLU on layers 0,1)
// R10 vs R9 (aggregates only):
//   - 128-thread blocks, 2 nodes/block: wave-duration imbalance ~30%->~12%
//     (R9 probe showed occupancy is NOT the limiter; imbalance is on top of
//     the fabric floor).
//   - quarter-wave layout: 16 lanes x half8 (16B dwordx4) per 128-dim row ->
//     4 rows in flight per load-issue, half the instructions per byte.
//     Two-stage butterfly combine (lane+16, lane+32), shfl always full-wave.
// R9: layer-2 fp16 Rh + single out write. R8: layer-2 linearity reorder.
// R7: deterministic counting-sort CSR. R3: fp16 MFMA GEMM pipeline.
// ---------------------------------------------------------------------------

#define D_H 128
#define NBUCKET 196          // ceil(50000/256) node buckets of 256
#define EPB 8192             // edges per histogram/scatter block
#define NBLK 98              // ceil(800000/8192)

typedef _Float16 half8  __attribute__((ext_vector_type(8)));
typedef _Float16 half4v __attribute__((ext_vector_type(4)));
typedef _Float16 half2v __attribute__((ext_vector_type(2)));
typedef float    floatx4 __attribute__((ext_vector_type(4)));

// ---------------- CSR build: deterministic counting sort (R7-proven) --------
__global__ __launch_bounds__(256) void hist_kernel(const int* __restrict__ dst,
                                                   int* __restrict__ histo, int E) {
    __shared__ int h[NBUCKET];
    for (int i = threadIdx.x; i < NBUCKET; i += 256) h[i] = 0;
    __syncthreads();
    int base = blockIdx.x * EPB;
    int end = min(base + EPB, E);
    for (int i = base + threadIdx.x; i < end; i += 256)
        atomicAdd(&h[dst[i] >> 8], 1);
    __syncthreads();
    for (int i = threadIdx.x; i < NBUCKET; i += 256)
        histo[blockIdx.x * NBUCKET + i] = h[i];
}

__global__ __launch_bounds__(256) void scan_hist_kernel(const int* __restrict__ histo,
                                                        int* __restrict__ offs,
                                                        int* __restrict__ boff,
                                                        int* __restrict__ row_ptr, int n) {
    __shared__ int s[256];
    int t = threadIdx.x;
    int sum = 0;
    if (t < NBUCKET) {
        for (int b = 0; b < NBLK; ++b) {
            offs[b * NBUCKET + t] = sum;
            sum += histo[b * NBUCKET + t];
        }
    }
    s[t] = (t < NBUCKET) ? sum : 0;
    int tot = s[t];
    __syncthreads();
    for (int off = 1; off < 256; off <<= 1) {
        int tmp = (t >= off) ? s[t - off] : 0;
        __syncthreads();
        s[t] += tmp;
        __syncthreads();
    }
    int base = s[t] - tot;
    if (t < NBUCKET) boff[t] = base;
    if (t == 255) { boff[NBUCKET] = s[255]; row_ptr[n] = s[255]; }
    __syncthreads();
    if (t < NBUCKET)
        for (int b = 0; b < NBLK; ++b)
            offs[b * NBUCKET + t] += base;
}

__global__ __launch_bounds__(256) void scatter_kernel(const int* __restrict__ src,
                                                      const int* __restrict__ dst,
                                                      const int* __restrict__ offs,
                                                      unsigned int* __restrict__ bedge, int E) {
    __shared__ int lcur[NBUCKET];
    for (int i = threadIdx.x; i < NBUCKET; i += 256)
        lcur[i] = offs[blockIdx.x * NBUCKET + i];
    __syncthreads();
    int base = blockIdx.x * EPB;
    int end = min(base + EPB, E);
    for (int i = base + threadIdx.x; i < end; i += 256) {
        int d = dst[i];
        int pos = atomicAdd(&lcur[d >> 8], 1);
        bedge[pos] = ((unsigned int)(d & 255) << 16) | (unsigned int)src[i];
    }
}

__global__ __launch_bounds__(256) void bucket_build_kernel(const unsigned int* __restrict__ bedge,
                                                           const int* __restrict__ boff,
                                                           int* __restrict__ row_ptr,
                                                           float* __restrict__ inv_deg,
                                                           int* __restrict__ col, int n) {
    __shared__ int sdeg[256];
    __shared__ int sscan[256];
    __shared__ int lcur[256];
    const int b = blockIdx.x;
    const int t = threadIdx.x;
    const int base = boff[b];
    const int bend = boff[b + 1];
    sdeg[t] = 0;
    __syncthreads();
    for (int i = base + t; i < bend; i += 256)
        atomicAdd(&sdeg[bedge[i] >> 16], 1);
    __syncthreads();
    int d = sdeg[t];
    sscan[t] = d;
    __syncthreads();
    for (int off = 1; off < 256; off <<= 1) {
        int tmp = (t >= off) ? sscan[t - off] : 0;
        __syncthreads();
        sscan[t] += tmp;
        __syncthreads();
    }
    int excl = sscan[t] - d;
    int node = b * 256 + t;
    if (node < n) {
        row_ptr[node] = base + excl;
        inv_deg[node] = 1.0f / (float)max(d, 1);
    }
    lcur[t] = excl;
    __syncthreads();
    for (int i = base + t; i < bend; i += 256) {
        unsigned int v = bedge[i];
        int pos = atomicAdd(&lcur[v >> 16], 1);
        col[base + pos] = (int)(v & 0xffffu);
    }
}

// ---------------- conversion: x (n4 float4s) + all 6 weight matrices --------
__global__ __launch_bounds__(256) void convert_all_kernel(
        const float* __restrict__ x, _Float16* __restrict__ xh, int n4,
        const float* __restrict__ w0, const float* __restrict__ w1,
        const float* __restrict__ w2, const float* __restrict__ w3,
        const float* __restrict__ w4, const float* __restrict__ w5,
        _Float16* __restrict__ o0, _Float16* __restrict__ o1,
        _Float16* __restrict__ o2, _Float16* __restrict__ o3,
        _Float16* __restrict__ o4, _Float16* __restrict__ o5) {
    int i = blockIdx.x * 256 + threadIdx.x;
    const float* in; _Float16* out; int j;
    if (i < n4) { in = x; out = xh; j = i; }
    else {
        int k = i - n4;
        if      (k <  4096) { in = w0; out = o0; j = k; }
        else if (k <  8192) { in = w1; out = o1; j = k - 4096; }
        else if (k < 12288) { in = w2; out = o2; j = k - 8192; }
        else if (k < 16384) { in = w3; out = o3; j = k - 12288; }
        else if (k < 18432) { in = w4; out = o4; j = k - 16384; }
        else if (k < 20480) { in = w5; out = o5; j = k - 18432; }
        else return;
    }
    float4 v = ((const float4*)in)[j];
    half4v o = { (_Float16)v.x, (_Float16)v.y, (_Float16)v.z, (_Float16)v.w };
    ((half4v*)out)[j] = o;
}

// ---------------- aggregate: mean of neighbor rows (128-dim) ----------------
// 2 nodes per 128-thread block (1 wave each; independent retire -> low
// imbalance). Quarter-wave: 16 lanes x half8 (16B) cover a 256B row; quarter q
// takes neighbors j = 4t + q -> 4 rows in flight per load-issue. Uniform loop
// bounds; shfl always full-wave (R6 rule). Combine: butterfly lane+16, lane+32.
__global__ __launch_bounds__(128, 8) void aggregate_kernel(const _Float16* __restrict__ h,
                                                           const int* __restrict__ row_ptr,
                                                           const int* __restrict__ col,
                                                           const float* __restrict__ inv_deg,
                                                           _Float16* __restrict__ agg, int n) {
    int wave = threadIdx.x >> 6;
    int lane = threadIdx.x & 63;
    int node = blockIdx.x * 2 + wave;
    if (node >= n) return;
    int beg = row_ptr[node];
    int end = row_ptr[node + 1];
    const int quarter = lane >> 4;
    const int off = (lane & 15) << 3;     // half8 slice: 16 lanes x 8 halves = 128
    float a0f = 0.f, a1f = 0.f, a2f = 0.f, a3f = 0.f;
    float a4f = 0.f, a5f = 0.f, a6f = 0.f, a7f = 0.f;
    for (int base = beg; base < end; base += 64) {
        int m = end - base;
        if (m > 64) m = 64;
        int myc = (lane < m) ? col[base + lane] : 0;
        int t = 0;
        // x4 main: uniform bound; j = 4(t+i)+quarter <= 4((m>>2)-1)+3 <= m-1.
        for (; t + 4 <= (m >> 2); t += 4) {
            int u0 = __shfl(myc, ((t + 0) << 2) + quarter);
            int u1 = __shfl(myc, ((t + 1) << 2) + quarter);
            int u2 = __shfl(myc, ((t + 2) << 2) + quarter);
            int u3 = __shfl(myc, ((t + 3) << 2) + quarter);
            half8 v0 = *(const half8*)&h[(size_t)u0 * D_H + off];
            half8 v1 = *(const half8*)&h[(size_t)u1 * D_H + off];
            half8 v2 = *(const half8*)&h[(size_t)u2 * D_H + off];
            half8 v3 = *(const half8*)&h[(size_t)u3 * D_H + off];
            a0f += (float)v0[0] + (float)v1[0] + (float)v2[0] + (float)v3[0];
            a1f += (float)v0[1] + (float)v1[1] + (float)v2[1] + (float)v3[1];
            a2f += (float)v0[2] + (float)v1[2] + (float)v2[2] + (float)v3[2];
            a3f += (float)v0[3] + (float)v1[3] + (float)v2[3] + (float)v3[3];
            a4f += (float)v0[4] + (float)v1[4] + (float)v2[4] + (float)v3[4];
            a5f += (float)v0[5] + (float)v1[5] + (float)v2[5] + (float)v3[5];
            a6f += (float)v0[6] + (float)v1[6] + (float)v2[6] + (float)v3[6];
            a7f += (float)v0[7] + (float)v1[7] + (float)v2[7] + (float)v3[7];
        }
        // uniform tail; shfl full-wave, load+add guarded (j < m)
        int smax = (m + 3) >> 2;
        for (; t < smax; ++t) {
            int j = (t << 2) + quarter;
            int u = __shfl(myc, j);
            if (j < m) {
                half8 v = *(const half8*)&h[(size_t)u * D_H + off];
                a0f += (float)v[0]; a1f += (float)v[1];
                a2f += (float)v[2]; a3f += (float)v[3];
                a4f += (float)v[4]; a5f += (float)v[5];
                a6f += (float)v[6]; a7f += (float)v[7];
            }
        }
    }
    // two-stage butterfly: lanes i, i+16, i+32, i+48 hold the same slice
    a0f += __shfl(a0f, lane + 16); a1f += __shfl(a1f, lane + 16);
    a2f += __shfl(a2f, lane + 16); a3f += __shfl(a3f, lane + 16);
    a4f += __shfl(a4f, lane + 16); a5f += __shfl(a5f, lane + 16);
    a6f += __shfl(a6f, lane + 16); a7f += __shfl(a7f, lane + 16);
    a0f += __shfl(a0f, lane + 32); a1f += __shfl(a1f, lane + 32);
    a2f += __shfl(a2f, lane + 32); a3f += __shfl(a3f, lane + 32);
    a4f += __shfl(a4f, lane + 32); a5f += __shfl(a5f, lane + 32);
    a6f += __shfl(a6f, lane + 32); a7f += __shfl(a7f, lane + 32);
    if (quarter == 0) {
        float s = inv_deg[node];
        half8 o = { (_Float16)(a0f * s), (_Float16)(a1f * s),
                    (_Float16)(a2f * s), (_Float16)(a3f * s),
                    (_Float16)(a4f * s), (_Float16)(a5f * s),
                    (_Float16)(a6f * s), (_Float16)(a7f * s) };
        *(half8*)&agg[(size_t)node * D_H + off] = o;
    }
}

// ---------------- layer-2 finish: out = Rh + inv_deg * sum T[neighbors] -----
// 64-dim rows (128B): 16 lanes x half4 (8B), quarter-wave, 2 nodes/block.
__global__ __launch_bounds__(128, 8) void aggregate_add64_kernel(
        const _Float16* __restrict__ T,
        const _Float16* __restrict__ Rh,
        const int* __restrict__ row_ptr,
        const int* __restrict__ col,
        const float* __restrict__ inv_deg,
        float* __restrict__ out, int n) {
    int wave = threadIdx.x >> 6;
    int lane = threadIdx.x & 63;
    int node = blockIdx.x * 2 + wave;
    if (node >= n) return;
    int beg = row_ptr[node];
    int end = row_ptr[node + 1];
    const int quarter = lane >> 4;
    const int off = (lane & 15) << 2;     // half4 slice: 16 lanes x 4 halves = 64
    float a0f = 0.f, a1f = 0.f, a2f = 0.f, a3f = 0.f;
    for (int base = beg; base < end; base += 64) {
        int m = end - base;
        if (m > 64) m = 64;
        int myc = (lane < m) ? col[base + lane] : 0;
        int t = 0;
        for (; t + 4 <= (m >> 2); t += 4) {
            int u0 = __shfl(myc, ((t + 0) << 2) + quarter);
            int u1 = __shfl(myc, ((t + 1) << 2) + quarter);
            int u2 = __shfl(myc, ((t + 2) << 2) + quarter);
            int u3 = __shfl(myc, ((t + 3) << 2) + quarter);
            half4v v0 = *(const half4v*)&T[(size_t)u0 * 64 + off];
            half4v v1 = *(const half4v*)&T[(size_t)u1 * 64 + off];
            half4v v2 = *(const half4v*)&T[(size_t)u2 * 64 + off];
            half4v v3 = *(const half4v*)&T[(size_t)u3 * 64 + off];
            a0f += (float)v0[0] + (float)v1[0] + (float)v2[0] + (float)v3[0];
            a1f += (float)v0[1] + (float)v1[1] + (float)v2[1] + (float)v3[1];
            a2f += (float)v0[2] + (float)v1[2] + (float)v2[2] + (float)v3[2];
            a3f += (float)v0[3] + (float)v1[3] + (float)v2[3] + (float)v3[3];
        }
        int smax = (m + 3) >> 2;
        for (; t < smax; ++t) {
            int j = (t << 2) + quarter;
            int u = __shfl(myc, j);
            if (j < m) {
                half4v v = *(const half4v*)&T[(size_t)u * 64 + off];
                a0f += (float)v[0]; a1f += (float)v[1];
                a2f += (float)v[2]; a3f += (float)v[3];
            }
        }
    }
    a0f += __shfl(a0f, lane + 16); a1f += __shfl(a1f, lane + 16);
    a2f += __shfl(a2f, lane + 16); a3f += __shfl(a3f, lane + 16);
    a0f += __shfl(a0f, lane + 32); a1f += __shfl(a1f, lane + 32);
    a2f += __shfl(a2f, lane + 32); a3f += __shfl(a3f, lane + 32);
    if (quarter == 0) {
        float s = inv_deg[node];
        half4v r = *(const half4v*)&Rh[(size_t)node * 64 + off];
        float4 o;
        o.x = (float)r[0] + a0f * s;
        o.y = (float)r[1] + a1f * s;
        o.z = (float)r[2] + a2f * s;
        o.w = (float)r[3] + a3f * s;
        *(float4*)&out[(size_t)node * 64 + off] = o;
    }
}

// ---------------- MFMA GEMM, layers 0/1 (R3-proven) ----------------
template<int NT, bool RELU_HALF_OUT>
__global__ __launch_bounds__(128) void gemm_mfma_kernel(
        const _Float16* __restrict__ Xa, const _Float16* __restrict__ Xh,
        const _Float16* __restrict__ Wa, const _Float16* __restrict__ Wh,
        const float* __restrict__ bias,
        _Float16* __restrict__ out_h, float* __restrict__ out_f, int N) {
    const int wave = threadIdx.x >> 6;
    const int lane = threadIdx.x & 63;
    const int r16 = lane & 15;
    const int quad = lane >> 4;
    const int base = blockIdx.x * 64 + wave * 32;
    const int koff = quad * 8;

    floatx4 acc[2][NT];
    #pragma unroll
    for (int s = 0; s < 2; ++s)
        #pragma unroll
        for (int j = 0; j < NT; ++j)
            acc[s][j] = (floatx4){0.f, 0.f, 0.f, 0.f};

    #pragma unroll
    for (int hsel = 0; hsel < 2; ++hsel) {
        const _Float16* __restrict__ X = hsel ? Xh : Xa;
        const _Float16* __restrict__ W = hsel ? Wh : Wa;
        #pragma unroll
        for (int k0 = 0; k0 < 128; k0 += 32) {
            half8 a0 = *(const half8*)&X[(size_t)(base + r16) * 128 + k0 + koff];
            half8 a1 = *(const half8*)&X[(size_t)(base + 16 + r16) * 128 + k0 + koff];
            #pragma unroll
            for (int j = 0; j < NT; ++j) {
                half8 b = *(const half8*)&W[(size_t)(j * 16 + r16) * 128 + k0 + koff];
                acc[0][j] = __builtin_amdgcn_mfma_f32_16x16x32_f16(a0, b, acc[0][j], 0, 0, 0);
                acc[1][j] = __builtin_amdgcn_mfma_f32_16x16x32_f16(a1, b, acc[1][j], 0, 0, 0);
            }
        }
    }

    #pragma unroll
    for (int s = 0; s < 2; ++s) {
        #pragma unroll
        for (int i = 0; i < 4; ++i) {
            int r = base + s * 16 + quad * 4 + i;
            if (r >= N) continue;
            #pragma unroll
            for (int j = 0; j < NT; ++j) {
                int c = j * 16 + r16;
                float v = acc[s][j][i] + bias[c];
                if (RELU_HALF_OUT) {
                    v = fmaxf(v, 0.f);
                    out_h[(size_t)r * (NT * 16) + c] = (_Float16)v;
                } else {
                    out_f[(size_t)r * (NT * 16) + c] = v;
                }
            }
        }
    }
}

// ---- dual GEMM, layer 2: T = B@Wl^T (fp16), Rh = B@Wr^T + bias (fp16) ----
__global__ __launch_bounds__(128) void gemm_dual_kernel(
        const _Float16* __restrict__ B, const _Float16* __restrict__ Wl,
        const _Float16* __restrict__ Wr, const float* __restrict__ bias,
        _Float16* __restrict__ T, _Float16* __restrict__ Rh, int N) {
    const int wave = threadIdx.x >> 6;
    const int lane = threadIdx.x & 63;
    const int r16 = lane & 15;
    const int quad = lane >> 4;
    const int base = blockIdx.x * 64 + wave * 32;
    const int koff = quad * 8;

    floatx4 accT[2][4], accR[2][4];
    #pragma unroll
    for (int s = 0; s < 2; ++s)
        #pragma unroll
        for (int j = 0; j < 4; ++j) {
            accT[s][j] = (floatx4){0.f, 0.f, 0.f, 0.f};
            accR[s][j] = (floatx4){0.f, 0.f, 0.f, 0.f};
        }

    #pragma unroll
    for (int k0 = 0; k0 < 128; k0 += 32) {
        half8 a0 = *(const half8*)&B[(size_t)(base + r16) * 128 + k0 + koff];
        half8 a1 = *(const half8*)&B[(size_t)(base + 16 + r16) * 128 + k0 + koff];
        #pragma unroll
        for (int j = 0; j < 4; ++j) {
            half8 bl = *(const half8*)&Wl[(size_t)(j * 16 + r16) * 128 + k0 + koff];
            half8 br = *(const half8*)&Wr[(size_t)(j * 16 + r16) * 128 + k0 + koff];
            accT[0][j] = __builtin_amdgcn_mfma_f32_16x16x32_f16(a0, bl, accT[0][j], 0, 0, 0);
            accT[1][j] = __builtin_amdgcn_mfma_f32_16x16x32_f16(a1, bl, accT[1][j], 0, 0, 0);
            accR[0][j] = __builtin_amdgcn_mfma_f32_16x16x32_f16(a0, br, accR[0][j], 0, 0, 0);
            accR[1][j] = __builtin_amdgcn_mfma_f32_16x16x32_f16(a1, br, accR[1][j], 0, 0, 0);
        }
    }

    #pragma unroll
    for (int s = 0; s < 2; ++s) {
        #pragma unroll
        for (int i = 0; i < 4; ++i) {
            int r = base + s * 16 + quad * 4 + i;
            if (r >= N) continue;
            #pragma unroll
            for (int j = 0; j < 4; ++j) {
                int c = j * 16 + r16;
                T[(size_t)r * 64 + c]  = (_Float16)accT[s][j][i];
                Rh[(size_t)r * 64 + c] = (_Float16)(accR[s][j][i] + bias[c]);
            }
        }
    }
}

extern "C" void kernel_launch(void* const* d_in, const int* in_sizes, int n_in,
                              void* d_out, int out_size, void* d_ws, size_t ws_size,
                              hipStream_t stream) {
    const float* x   = (const float*)d_in[0];
    const int*   edge = (const int*)d_in[1];   // int32: [2, E]
    const float* Wl0 = (const float*)d_in[2];
    const float* bl0 = (const float*)d_in[3];
    const float* Wr0 = (const float*)d_in[4];
    const float* Wl1 = (const float*)d_in[5];
    const float* bl1 = (const float*)d_in[6];
    const float* Wr1 = (const float*)d_in[7];
    const float* Wl2 = (const float*)d_in[8];
    const float* bl2 = (const float*)d_in[9];
    const float* Wr2 = (const float*)d_in[10];
    float* out = (float*)d_out;

    const int N = in_sizes[0] / D_H;   // 50000
    const int E = in_sizes[1] / 2;     // 800000
    const int* src = edge;
    const int* dst = edge + E;

    const int gx = (N + 63) / 64;
    const int Np = gx * 64;
    const size_t HBYTES = (size_t)Np * D_H * 2;   // 12.8MB per fp16 node matrix

    // ---- time-multiplexed workspace (~42MB) ----
    char* w = (char*)d_ws;
    char* P0 = w;  w += HBYTES;
    char* P1 = w;  w += HBYTES;
    char* P2 = w;  w += HBYTES;
    _Float16* Wl0h = (_Float16*)w;  w += (size_t)128 * 128 * 2;
    _Float16* Wr0h = (_Float16*)w;  w += (size_t)128 * 128 * 2;
    _Float16* Wl1h = (_Float16*)w;  w += (size_t)128 * 128 * 2;
    _Float16* Wr1h = (_Float16*)w;  w += (size_t)128 * 128 * 2;
    _Float16* Wl2h = (_Float16*)w;  w += (size_t)64 * 128 * 2;
    _Float16* Wr2h = (_Float16*)w;  w += (size_t)64 * 128 * 2;
    int* row_ptr = (int*)w;      w += (size_t)(N + 16) * 4;
    float* inv_deg = (float*)w;  w += (size_t)N * 4;
    int* col     = (int*)w;      w += (size_t)E * 4;
    int* histo   = (int*)w;      w += (size_t)NBLK * NBUCKET * 4;
    int* offs    = (int*)w;      w += (size_t)NBLK * NBUCKET * 4;
    int* boff    = (int*)w;      w += (size_t)(NBUCKET + 1) * 4;

    _Float16* xh   = (_Float16*)P0;
    _Float16* Bh   = (_Float16*)P0;          // xh dead after layer-0 GEMM
    unsigned int* bedge = (unsigned int*)P1; // 3.2MB, dead after bucket_build
    _Float16* Ah   = (_Float16*)P1;
    _Float16* aggh = (_Float16*)P2;          // dead after layer-1 GEMM
    _Float16* T    = (_Float16*)P2;                       // layer-2 T (6.4MB)
    _Float16* Rh   = (_Float16*)(P2 + HBYTES / 2);        // layer-2 Rh (6.4MB)

    // ---- CSR build: counting sort (no global atomics) ----
    hist_kernel<<<NBLK, 256, 0, stream>>>(dst, histo, E);
    scan_hist_kernel<<<1, 256, 0, stream>>>(histo, offs, boff, row_ptr, N);
    scatter_kernel<<<NBLK, 256, 0, stream>>>(src, dst, offs, bedge, E);
    bucket_build_kernel<<<NBUCKET, 256, 0, stream>>>(bedge, boff, row_ptr, inv_deg, col, N);

    // ---- fp32 -> fp16 conversions (x + all weights, one dispatch) ----
    const int n4 = N * D_H / 4;
    const int ctotal = n4 + 20480;
    convert_all_kernel<<<(ctotal + 255) / 256, 256, 0, stream>>>(
        x, xh, n4, Wl0, Wr0, Wl1, Wr1, Wl2, Wr2,
        Wl0h, Wr0h, Wl1h, Wr1h, Wl2h, Wr2h);

    const int agg_grid = (N + 1) / 2;     // 2 nodes per 128-thread block

    // ---- layer 0: xh -> Ah (relu) ----
    aggregate_kernel<<<agg_grid, 128, 0, stream>>>(xh, row_ptr, col, inv_deg, aggh, N);
    gemm_mfma_kernel<8, true><<<gx, 128, 0, stream>>>(aggh, xh, Wl0h, Wr0h, bl0, Ah, nullptr, N);

    // ---- layer 1: Ah -> Bh (relu; Bh overwrites xh region) ----
    aggregate_kernel<<<agg_grid, 128, 0, stream>>>(Ah, row_ptr, col, inv_deg, aggh, N);
    gemm_mfma_kernel<8, true><<<gx, 128, 0, stream>>>(aggh, Ah, Wl1h, Wr1h, bl1, Bh, nullptr, N);

    // ---- layer 2 (reordered): T = Bh@Wl2^T, Rh = Bh@Wr2^T + bias (both fp16),
    //      then out = Rh + inv_deg * (A @ T) with 64-dim (128B) gathers ----
    gemm_dual_kernel<<<gx, 128, 0, stream>>>(Bh, Wl2h, Wr2h, bl2, T, Rh, N);
    aggregate_add64_kernel<<<agg_grid, 128, 0, stream>>>(T, Rh, row_ptr, col, inv_deg, out, N);
}